// Round 3
// baseline (3230.400 us; speedup 1.0000x reference)
//
#include <hip/hip_runtime.h>
#include <hip/hip_bf16.h>
#include <cstddef>
#include <cstdint>

namespace {

constexpr int B = 2048, T = 128, F = 128, H = 512, L = 8, KW = 10;
constexpr int GATES = 2064;
constexpr int NG = 2048;    // gate columns (permuted)
constexpr int KIN = 640;    // F + H
constexpr int HS = 85;      // H // 6
constexpr int RC = H * KW;  // 5120
constexpr int KS = 8;       // conv split-K slices
constexpr int NROW = 144;   // WgT rows per tile: 128 gates + 16 logit cols

// LDS layout for persistent_step (exactly 160 KiB, 1 block/CU):
constexpr int BSLICE = 8192;     // one B k-slice: 128 rows x 32 k bf16
constexpr int NRES = 18;         // resident slices 0..17 @ 0..147456
constexpr int RINGA = 147456;    // slice 18 (re-staged during spin)
constexpr int RINGB = 155648;    // slice 19 (re-staged during spin)
// epilogue scratch aliases ring slots (dead windows verified):
constexpr int LOGO  = 147456;    // logitS 128*17*4 = 8704 B (post-k .. softmax)
constexpr int HSTO  = 147456;    // hstage 8192 B (gates .. pack; logitS dead)
constexpr int DTSO2 = 156160;    // dts 512 B (post-k .. gates)
constexpr int FMIMO = 156672;    // fmim 128*2*4 = 1024 B (softmax .. gates)
constexpr int SMEM_SZ = 163840;

typedef __attribute__((ext_vector_type(8))) short short8;
typedef __attribute__((ext_vector_type(4))) float f32x4;
typedef unsigned long long ull;

__device__ __forceinline__ float fsigmoid_(float x) {
    return __builtin_amdgcn_rcpf(1.0f + __expf(-x));
}
__device__ __forceinline__ float ftanh_(float x) {
    return 1.0f - 2.0f * __builtin_amdgcn_rcpf(1.0f + __expf(2.0f * x));
}

__device__ __forceinline__ void gl_lds16(const void* g, void* l) {
    __builtin_amdgcn_global_load_lds(
        (const __attribute__((address_space(1))) unsigned int*)g,
        (__attribute__((address_space(3))) unsigned int*)l,
        16, 0, 0);
}

__device__ __forceinline__ ull h_atomic_load(const void* p) {
    return __hip_atomic_load((const ull*)p, __ATOMIC_RELAXED, __HIP_MEMORY_SCOPE_AGENT);
}

// ---------- prep (unchanged) ----------
__global__ __launch_bounds__(256) void prep_wgt(
    const float* __restrict__ Wk, const float* __restrict__ Wr,
    __hip_bfloat16* __restrict__ WgT)
{
    __shared__ float tile[64 * 65];
    const int tid = threadIdx.x;
    const int c0 = blockIdx.x * 64, k0 = blockIdx.y * 64;
#pragma unroll
    for (int rep = 0; rep < 16; ++rep) {
        int e = rep * 256 + tid;
        int kl = e >> 6, cl = e & 63;
        int col = c0 + cl;
        int nt = col >> 7, cc = col & 127;
        int n = 16 + ((cc >> 4) & 3) * 512 + nt * 32 + ((cc >> 6) & 1) * 16 + (cc & 15);
        int k = k0 + kl;
        tile[kl * 65 + cl] = (k < F) ? Wk[(size_t)k * GATES + n] : Wr[(size_t)(k - F) * GATES + n];
    }
    __syncthreads();
    const int cl = tid >> 2, q = tid & 3;
    unsigned short buf[16];
#pragma unroll
    for (int i = 0; i < 16; ++i) {
        float f = tile[(q * 16 + i) * 65 + cl];
        __hip_bfloat16 bv = __float2bfloat16(f);
        buf[i] = *(unsigned short*)&bv;
    }
    int col = c0 + cl;
    int nt = col >> 7, rin = col & 127;
    unsigned short* dst = (unsigned short*)WgT + (size_t)nt * NROW * KIN + (size_t)rin * KIN + k0 + q * 16;
    *(short8*)dst = *(short8*)&buf[0];
    *(short8*)(dst + 8) = *(short8*)&buf[8];
}

__global__ void prep_w16rep(const float* __restrict__ Wk, const float* __restrict__ Wr,
                            __hip_bfloat16* __restrict__ WgT)
{
    int idx = blockIdx.x * blockDim.x + threadIdx.x;
    if (idx >= 16 * 16 * KIN) return;
    int nt = idx / (16 * KIN);
    int rem = idx % (16 * KIN);
    int n = rem / KIN, k = rem % KIN;
    float v = (k < F) ? Wk[(size_t)k * GATES + n] : Wr[(size_t)(k - F) * GATES + n];
    WgT[(size_t)nt * NROW * KIN + (size_t)(128 + n) * KIN + k] = __float2bfloat16(v);
}

__global__ void prep_small(const float* __restrict__ Wk, const float* __restrict__ bk,
                           const float* __restrict__ Wr, const float* __restrict__ br,
                           float* __restrict__ biasg, float* __restrict__ wrowg,
                           float* __restrict__ bias16, float* __restrict__ wrow16)
{
    const int total = 2 * NG + 32;
    for (int idx = threadIdx.x; idx < total; idx += 256) {
        if (idx < NG) {
            int col = idx;
            int nt = col >> 7, cc = col & 127;
            int n = 16 + ((cc >> 4) & 3) * 512 + nt * 32 + ((cc >> 6) & 1) * 16 + (cc & 15);
            biasg[col] = bk[n] + br[n];
        } else if (idx < 2 * NG) {
            int col = idx - NG;
            int nt = col >> 7, cc = col & 127;
            int n = 16 + ((cc >> 4) & 3) * 512 + nt * 32 + ((cc >> 6) & 1) * 16 + (cc & 15);
            wrowg[col] = Wk[(size_t)F * GATES + n] + Wr[(size_t)H * GATES + n];
        } else if (idx < 2 * NG + 16) {
            int n = idx - 2 * NG;
            bias16[n] = bk[n] + br[n];
        } else {
            int n = idx - 2 * NG - 16;
            wrow16[n] = Wk[(size_t)F * GATES + n] + Wr[(size_t)H * GATES + n];
        }
    }
}

__global__ void convert_x(const float* __restrict__ x, __hip_bfloat16* __restrict__ xb) {
    int i = blockIdx.x * blockDim.x + threadIdx.x;
    size_t o = (size_t)i * 4;
    if (o >= (size_t)B * T * F) return;
    float4 v = *(const float4*)(x + o);
    xb[o + 0] = __float2bfloat16(v.x);
    xb[o + 1] = __float2bfloat16(v.y);
    xb[o + 2] = __float2bfloat16(v.z);
    xb[o + 3] = __float2bfloat16(v.w);
}

__global__ void prep_convw(const float* __restrict__ conv_w, __hip_bfloat16* __restrict__ CWb) {
    int i = blockIdx.x * blockDim.x + threadIdx.x;
    if (i >= H * RC / 4) return;
    size_t o = (size_t)i * 4;
    float4 v = *(const float4*)(conv_w + o);
    CWb[o + 0] = __float2bfloat16(v.x);
    CWb[o + 1] = __float2bfloat16(v.y);
    CWb[o + 2] = __float2bfloat16(v.z);
    CWb[o + 3] = __float2bfloat16(v.w);
}

// tme [B,T] -> tmeT [T,B]
__global__ __launch_bounds__(256) void prep_tmet(const float* __restrict__ tin,
                                                 float* __restrict__ tout)
{
    __shared__ float tl[32][33];
    const int bb = blockIdx.x * 32, tt = blockIdx.y * 32;
    const int tx = threadIdx.x & 31, ty = threadIdx.x >> 5;
#pragma unroll
    for (int r = 0; r < 32; r += 8)
        tl[ty + r][tx] = tin[(size_t)(bb + ty + r) * T + tt + tx];
    __syncthreads();
#pragma unroll
    for (int r = 0; r < 32; r += 8)
        tout[(size_t)(tt + ty + r) * B + bb + tx] = tl[tx][ty + r];
}

// ---------- persistent fused step ----------
struct StepArgs {
    const __hip_bfloat16* xb;
    __hip_bfloat16* h0;
    __hip_bfloat16* h1;
    const __hip_bfloat16* WgT;
    const float* biasg;
    const float* wrowg;
    const float* bias16;
    const float* wrow16;
    const float* tmeT;   // [T, B]
    __hip_bfloat16* tmp_h;
    float* tmp_ds;
    float* dist_out;
    unsigned* bar;  // per-mt-group counters, 256 B apart
};

// 256 blocks (16 mt x 16 nt, XCD-swizzled), 512 threads.
// R11: BARRIER-FREE k-loop. A frags loaded direct global->VGPR in MFMA frag
// layout (x plain, h via 8B relaxed-atomic), 3-slot pipeline 2 iters ahead,
// compiler waitcnts. B gates fully LDS-resident: 18 slices staged once + 2
// ring slots re-staged during the inter-step spin. Logit-B (16x640) resident
// in wc0-wave VGPRs. Waves free-run through all 20 iters (no s_barrier, no
// manual vmcnt). Epilogue scratch aliases ring slots; lidx==nt>>1 is
// block-constant so fmim is 2 floats/row. 6 barriers/step (was 26).
__global__ __launch_bounds__(512, 2) void persistent_step(StepArgs a)
{
    __shared__ __align__(16) char smem[SMEM_SZ];
    float* logitS = (float*)(smem + LOGO);
    float* fmimS  = (float*)(smem + FMIMO);
    unsigned short* hstageS = (unsigned short*)(smem + HSTO);
    float* dts = (float*)(smem + DTSO2);

    const int tid = threadIdx.x;
    const int wave = tid >> 6;
    const int wr = wave >> 1, wc = wave & 1;   // wr 0..3, wc 0..1
    const int quad = (tid & 63) >> 4, m16 = tid & 15;
    const int l = blockIdx.x;
    const int nt = ((l & 7) << 1) | ((l >> 3) & 1);  // same-nt -> same XCD
    const int mt = l >> 4;
    const int m0 = mt * 128;
    const int lidx = nt >> 1;   // block-constant chunk index

    // ---- B slice DMA geometry (gate rows 0..127; 8192 B per slice)
    const int o0 = tid * 16;
    const int brow0 = o0 >> 6;
    const int bsl0 = ((((o0 >> 4) & 3) ^ ((brow0 >> 1) & 3)) << 3);
    const unsigned short* wgt_tile = (const unsigned short*)a.WgT + (size_t)nt * NROW * KIN;
    const char* bsT0 = (const char*)(wgt_tile + (size_t)brow0 * KIN + bsl0);
    auto stageB = [&](int s, int off) {
        gl_lds16(bsT0 + s * 64, smem + off + o0);
    };

    // ---- A-frag per-lane global addressing (frag layout: row base+m16,
    // k = 32*ki + 8*quad)
    const int arow0 = m0 + wr * 32 + m16;
    const char* xA0 = (const char*)a.xb + (size_t)arow0 * (T * F * 2) + quad * 16;
    const char* xA1 = xA0 + (size_t)16 * (T * F * 2);
    const size_t hA0 = (size_t)arow0 * (H * 2) + quad * 16;
    const size_t hA1 = hA0 + (size_t)16 * (H * 2);

    // ---- logit-B resident in VGPRs (wc==0 waves), t-invariant
    ull wv20[20][2];
    if (wc == 0) {
        const unsigned short* lrow = wgt_tile + (size_t)(128 + m16) * KIN + quad * 8;
#pragma unroll
        for (int s = 0; s < 20; ++s) {
            wv20[s][0] = *(const ull*)(lrow + s * 32);
            wv20[s][1] = *(const ull*)(lrow + s * 32 + 4);
        }
    }

    // ---- t-invariant epilogue constants
    const int hcol = nt * 32 + wc * 16 + m16;
    float bj[4], wj[4];
#pragma unroll
    for (int j = 0; j < 4; ++j) {
        int col = nt * 128 + wc * 64 + j * 16 + m16;
        bj[j] = a.biasg[col];
        wj[j] = a.wrowg[col];
    }
    const int soff = (tid >= 128 && tid < 256) ? 8 : 0;
    float b16r8[8], w16r8[8];
#pragma unroll
    for (int n = 0; n < 8; ++n) { b16r8[n] = a.bias16[soff + n]; w16r8[n] = a.wrow16[soff + n]; }

    float creg[2][4] = {};
    ull af[3][2][2];   // [slot][frag][half]

    // ---- prologue: stage all B slices; preload A iters 0,1 of t=0
    {
#pragma unroll
        for (int s = 0; s < NRES; ++s) stageB(s, s * BSLICE);
        stageB(18, RINGA);
        stageB(19, RINGB);
        af[0][0][0] = *(const ull*)(xA0);      af[0][0][1] = *(const ull*)(xA0 + 8);
        af[0][1][0] = *(const ull*)(xA1);      af[0][1][1] = *(const ull*)(xA1 + 8);
        af[1][0][0] = *(const ull*)(xA0 + 64); af[1][0][1] = *(const ull*)(xA0 + 72);
        af[1][1][0] = *(const ull*)(xA1 + 64); af[1][1][1] = *(const ull*)(xA1 + 72);
    }
    __syncthreads();  // drain prologue staging

#pragma unroll 1
    for (int t = 0; t < T; ++t) {
        const char* xt0 = xA0 + (size_t)t * 256;
        const char* xt1 = xA1 + (size_t)t * 256;
        const char* hbuf = (const char*)((t & 1) ? a.h1 : a.h0);
        unsigned* hout32 = (unsigned*)((t & 1) ? a.h0 : a.h1);

        float dtreg = 0.f;
        if (tid < 128) dtreg = a.tmeT[(size_t)t * B + m0 + tid];

        f32x4 acc[2][4] = {};
        f32x4 acc16[2] = {};

        // ---- barrier-free k-loop: 20 iters, waves free-run
#pragma unroll
        for (int ki = 0; ki < 20; ++ki) {
            const int ld = ki + 2;
            if (ld < 20) {
                const int slot = ld % 3;
                if (ld <= 3) {
                    af[slot][0][0] = *(const ull*)(xt0 + ld * 64);
                    af[slot][0][1] = *(const ull*)(xt0 + ld * 64 + 8);
                    af[slot][1][0] = *(const ull*)(xt1 + ld * 64);
                    af[slot][1][1] = *(const ull*)(xt1 + ld * 64 + 8);
                } else {
                    const size_t ko = (size_t)ld * 64 - 256;
                    af[slot][0][0] = h_atomic_load(hbuf + hA0 + ko);
                    af[slot][0][1] = h_atomic_load(hbuf + hA0 + ko + 8);
                    af[slot][1][0] = h_atomic_load(hbuf + hA1 + ko);
                    af[slot][1][1] = h_atomic_load(hbuf + hA1 + ko + 8);
                }
            }
            const unsigned short* Bb = (const unsigned short*)(smem +
                (ki < NRES ? ki * BSLICE : (ki == 18 ? RINGA : RINGB)));
            short8 bvv[4];
#pragma unroll
            for (int j = 0; j < 4; ++j) {
                int br = wc * 64 + j * 16 + m16;
                bvv[j] = *(const short8*)&Bb[br * 32 + ((quad ^ ((br >> 1) & 3)) << 3)];
            }
            short8 av0, av1;
            ((ull*)&av0)[0] = af[ki % 3][0][0]; ((ull*)&av0)[1] = af[ki % 3][0][1];
            ((ull*)&av1)[0] = af[ki % 3][1][0]; ((ull*)&av1)[1] = af[ki % 3][1][1];
#pragma unroll
            for (int j = 0; j < 4; ++j) {
                acc[0][j] = __builtin_amdgcn_mfma_f32_16x16x32_bf16(av0, bvv[j], acc[0][j], 0, 0, 0);
                acc[1][j] = __builtin_amdgcn_mfma_f32_16x16x32_bf16(av1, bvv[j], acc[1][j], 0, 0, 0);
            }
            if (wc == 0) {
                short8 wv;
                ((ull*)&wv)[0] = wv20[ki][0]; ((ull*)&wv)[1] = wv20[ki][1];
                acc16[0] = __builtin_amdgcn_mfma_f32_16x16x32_bf16(av0, wv, acc16[0], 0, 0, 0);
                acc16[1] = __builtin_amdgcn_mfma_f32_16x16x32_bf16(av1, wv, acc16[1], 0, 0, 0);
            }
        }
        __syncthreads();  // all waves done with ring-slot reads; scratch safe

        // logits + dts -> LDS
        if (tid < 128) dts[tid] = dtreg;
        if (wc == 0) {
#pragma unroll
            for (int i = 0; i < 2; ++i)
#pragma unroll
                for (int r = 0; r < 4; ++r)
                    logitS[(wr * 32 + i * 16 + quad * 4 + r) * 17 + m16] = acc16[i][r];
        }
        __syncthreads();

        // per-row softmax-cumsum: fm half tid<128, im half tid 128..255.
        // Only position lidx = nt>>1 is needed per block (+ fsum for dist).
        if (tid < 256) {
            const int row = tid & 127;
            const int m = m0 + row;
            const bool hi = tid >= 128;
            const float dt = hi ? dts[row] : dtreg;
            float z[8];
#pragma unroll
            for (int n = 0; n < 8; ++n)
                z[n] = logitS[row * 17 + soff + n] + b16r8[n] + dt * w16r8[n];
            float mx = z[0];
#pragma unroll
            for (int j = 1; j < 8; ++j) mx = fmaxf(mx, z[j]);
            float e[8], s = 0.f;
#pragma unroll
            for (int j = 0; j < 8; ++j) { e[j] = __expf(z[j] - mx); s += e[j]; }
            const float inv = __builtin_amdgcn_rcpf(s);
            if (!hi) {
                float run = 0.f, fsum = 0.f, val = 0.f;
#pragma unroll
                for (int j = 0; j < 8; ++j) {
                    run += e[j];
                    float fmv = run * inv;
                    if (j == lidx) val = fmv;
                    fsum += fmv;
                }
                fmimS[row * 2] = val;
                if (nt == 0) {
                    float d = 1.0f - fsum * 0.125f;
                    a.dist_out[(size_t)t * B + m] = d;
                    if (t >= T - KW) a.tmp_ds[(size_t)(t - (T - KW)) * B + m] = d;
                }
            } else {
                float run = 0.f, val = 0.f;
#pragma unroll
                for (int j = 7; j >= 0; --j) {
                    run += e[j];
                    if (j == lidx) val = run * inv;
                }
                fmimS[row * 2 + 1] = val;
            }
        }
        __syncthreads();

        // gates + cell update (c in regs); h -> LDS stage (aliases logitS)
#pragma unroll
        for (int i = 0; i < 2; ++i) {
#pragma unroll
            for (int r = 0; r < 4; ++r) {
                int rl = wr * 32 + i * 16 + quad * 4 + r;
                int m = m0 + rl;
                float dt = dts[rl];
                float fmv = fmimS[rl * 2];
                float imv = fmimS[rl * 2 + 1];
                float fg = fsigmoid_(acc[i][0][r] + bj[0] + dt * wj[0]);
                float ig = fsigmoid_(acc[i][1][r] + bj[1] + dt * wj[1]);
                float og = fsigmoid_(acc[i][2][r] + bj[2] + dt * wj[2]);
                float ci = ftanh_(acc[i][3][r] + bj[3] + dt * wj[3]);
                float ov = fmv * imv;
                float cl = creg[i][r];
                float cn = ov * (fg * cl + ig * ci) + (fmv - ov) * cl + (imv - ov) * ci;
                float hn = og * ftanh_(cn);
                creg[i][r] = cn;
                __hip_bfloat16 hb = __float2bfloat16(hn);
                hstageS[rl * 32 + (wc * 16 + m16)] = *(unsigned short*)&hb;
                if (t >= T - KW) a.tmp_h[((size_t)(t - (T - KW)) * B + m) * H + hcol] = hb;
            }
        }
        __syncthreads();

        // pack h pairs -> agent-scope atomic dword stores
        {
            const unsigned* hs32 = (const unsigned*)hstageS;
#pragma unroll
            for (int wds = 0; wds < 4; ++wds) {
                int wi = wds * 512 + tid;
                int row = wi >> 4, cp = wi & 15;
                unsigned v = hs32[row * 16 + cp];
                __hip_atomic_store(hout32 + (size_t)(m0 + row) * (H / 2) + nt * 16 + cp, v,
                                   __ATOMIC_RELAXED, __HIP_MEMORY_SCOPE_AGENT);
            }
        }

        __syncthreads();  // pack reads done + h stores drained
        if (t != T - 1) {
            // pre-issue: ring slices + next step's A iters 0,1 (fly in spin)
            const char* xn0 = xA0 + (size_t)(t + 1) * 256;
            const char* xn1 = xA1 + (size_t)(t + 1) * 256;
            stageB(18, RINGA);
            stageB(19, RINGB);
            af[0][0][0] = *(const ull*)(xn0);      af[0][0][1] = *(const ull*)(xn0 + 8);
            af[0][1][0] = *(const ull*)(xn1);      af[0][1][1] = *(const ull*)(xn1 + 8);
            af[1][0][0] = *(const ull*)(xn0 + 64); af[1][0][1] = *(const ull*)(xn0 + 72);
            af[1][1][0] = *(const ull*)(xn1 + 64); af[1][1][1] = *(const ull*)(xn1 + 72);
            // per-mt-group barrier (16 nt blocks = closed h-communication set)
            if (tid == 0) {
                unsigned* ctr = a.bar + (mt << 6);
                __hip_atomic_fetch_add(ctr, 1u, __ATOMIC_RELAXED, __HIP_MEMORY_SCOPE_AGENT);
                const unsigned tgt = 16u * (unsigned)(t + 1);
                for (int it = 0; it < (1 << 22); ++it) {
                    if (__hip_atomic_load(ctr, __ATOMIC_RELAXED, __HIP_MEMORY_SCOPE_AGENT) >= tgt) break;
                    __builtin_amdgcn_s_sleep(2);
                }
            }
            __syncthreads();  // releases block + drains pre-issued staging
        }
    }
}

// ---------- post (unchanged) ----------
__global__ __launch_bounds__(128) void post_local(
    const __hip_bfloat16* __restrict__ tmp_h, const float* __restrict__ tmp_dis,
    float* __restrict__ mean_h, __hip_bfloat16* __restrict__ Ahk)
{
    const int b = blockIdx.x;
    const int tid = threadIdx.x;
    __shared__ float ld[KW];
    if (tid == 0) {
        float cd[KW];
        float run = 0.f;
        for (int k = 0; k < KW; ++k) { run += tmp_dis[(size_t)k * B + b]; cd[k] = run; }
        float mx = cd[0];
        for (int k = 1; k < KW; ++k) mx = fmaxf(mx, cd[k]);
        float s = 0.f;
        for (int k = 0; k < KW; ++k) { cd[k] = expf(cd[k] - mx); s += cd[k]; }
        for (int k = 0; k < KW; ++k) ld[k] = cd[k] / s;
    }
    __syncthreads();
    float ldr[KW];
#pragma unroll
    for (int k = 0; k < KW; ++k) ldr[k] = ld[k];
    for (int h = tid; h < H; h += 128) {
        float s = 0.f;
#pragma unroll
        for (int k = 0; k < KW; ++k) {
            float v = __bfloat162float(tmp_h[((size_t)k * B + b) * H + h]) * ldr[k];
            s += v;
            Ahk[(size_t)b * RC + h * KW + k] = __float2bfloat16(v);
        }
        mean_h[(size_t)b * H + h] = s * (1.0f / KW);
    }
}

__global__ void theme1_k(const float* __restrict__ mean_h, const float* __restrict__ Ws,
                         const float* __restrict__ bs, float* __restrict__ t1)
{
    int idx = blockIdx.x * blockDim.x + threadIdx.x;
    if (idx >= B * HS) return;
    int b = idx / HS, j = idx % HS;
    float s = bs[j];
    const float* mh = mean_h + (size_t)b * H;
    for (int h = 0; h < H; ++h) s += mh[h] * Ws[(size_t)h * HS + j];
    t1[idx] = fmaxf(s, 0.f);
}

__global__ void theme2_k(const float* __restrict__ t1, const float* __restrict__ Wrs,
                         const float* __restrict__ brs, float* __restrict__ theme)
{
    int idx = blockIdx.x * blockDim.x + threadIdx.x;
    if (idx >= B * H) return;
    int b = idx / H, o = idx % H;
    float s = brs[o];
    const float* tv = t1 + (size_t)b * HS;
    for (int j = 0; j < HS; ++j) s += tv[j] * Wrs[(size_t)j * H + o];
    theme[idx] = 1.0f / (1.0f + expf(-s));
}

__global__ __launch_bounds__(256) void conv_split(
    const __hip_bfloat16* __restrict__ Ahk, const __hip_bfloat16* __restrict__ CWb,
    float* __restrict__ Pbuf)
{
    __shared__ __align__(16) unsigned short As2[128 * 64];
    __shared__ __align__(16) unsigned short Bs2[128 * 64];
    const int tid = threadIdx.x;
    const int wave = tid >> 6;
    const int wr = wave >> 1, wc = wave & 1;
    const int quad = (tid & 63) >> 4, m16 = tid & 15;
    const int n0 = blockIdx.x * 128, m0 = blockIdx.y * 128;
    const int ksb = blockIdx.z * (RC / KS);

    f32x4 acc[4][4] = {};
    for (int k0 = 0; k0 < RC / KS; k0 += 64) {
#pragma unroll
        for (int p = 0; p < 4; ++p) {
            int o = p * 4096 + tid * 16;
            int row = o >> 7, slot = (o >> 4) & 7;
            int kg = ksb + k0 + (slot ^ (row & 7)) * 8;
            gl_lds16((const unsigned short*)Ahk + (size_t)(m0 + row) * RC + kg, (char*)As2 + o);
            gl_lds16((const unsigned short*)CWb + (size_t)(n0 + row) * RC + kg, (char*)Bs2 + o);
        }
        __syncthreads();
#pragma unroll
        for (int c2 = 0; c2 < 2; ++c2) {
            const int k8 = c2 * 4 + quad;
            short8 av[4], bv[4];
#pragma unroll
            for (int i = 0; i < 4; ++i) {
                int arow = wr * 64 + i * 16 + m16;
                av[i] = *(const short8*)&As2[arow * 64 + (k8 ^ (arow & 7)) * 8];
            }
#pragma unroll
            for (int j = 0; j < 4; ++j) {
                int brow = wc * 64 + j * 16 + m16;
                bv[j] = *(const short8*)&Bs2[brow * 64 + (k8 ^ (brow & 7)) * 8];
            }
#pragma unroll
            for (int i = 0; i < 4; ++i)
#pragma unroll
                for (int j = 0; j < 4; ++j)
                    acc[i][j] = __builtin_amdgcn_mfma_f32_16x16x32_bf16(av[i], bv[j], acc[i][j], 0, 0, 0);
        }
        __syncthreads();
    }
    float* P = Pbuf + (size_t)blockIdx.z * B * H;
#pragma unroll
    for (int j = 0; j < 4; ++j) {
        const int col = n0 + wc * 64 + j * 16 + m16;
#pragma unroll
        for (int i = 0; i < 4; ++i) {
            const int rb = m0 + wr * 64 + i * 16 + quad * 4;
#pragma unroll
            for (int r = 0; r < 4; ++r)
                P[(size_t)(rb + r) * H + col] = acc[i][j][r];
        }
    }
}

__global__ void conv_reduce(const float* __restrict__ Pbuf, const float* __restrict__ conv_b,
                            const float* __restrict__ theme, float* __restrict__ out0)
{
    int i = blockIdx.x * blockDim.x + threadIdx.x;
    if (i >= B * H) return;
    float s = conv_b[i & (H - 1)];
#pragma unroll
    for (int ks = 0; ks < KS; ++ks) s += Pbuf[(size_t)ks * B * H + i];
    out0[i] = theme[i] * s;
}

} // namespace

extern "C" void kernel_launch(void* const* d_in, const int* in_sizes, int n_in,
                              void* d_out, int out_size, void* d_ws, size_t ws_size,
                              hipStream_t stream)
{
    (void)in_sizes; (void)n_in; (void)out_size; (void)ws_size;
    const float* x      = (const float*)d_in[0];
    const float* tme    = (const float*)d_in[1];
    const float* Wk     = (const float*)d_in[2];
    const float* bk     = (const float*)d_in[3];
    const float* Wr     = (const float*)d_in[4];
    const float* br     = (const float*)d_in[5];
    const float* Ws     = (const float*)d_in[6];
    const float* bs     = (const float*)d_in[7];
    const float* Wrs    = (const float*)d_in[8];
    const float* brs    = (const float*)d_in[9];
    const float* conv_w = (const float*)d_in[10];
    const float* conv_b = (const float*)d_in[11];

    float* out0 = (float*)d_out;
    float* dist_out = out0 + (size_t)B * H;

    // workspace carve (~163 MB)
    char* w = (char*)d_ws;
    __hip_bfloat16* WgT  = (__hip_bfloat16*)w; w += (size_t)16 * NROW * KIN * 2;
    __hip_bfloat16* xb   = (__hip_bfloat16*)w; w += (size_t)B * T * F * 2;
    __hip_bfloat16* CWb  = (__hip_bfloat16*)w; w += (size_t)H * RC * 2;
    __hip_bfloat16* Ahk  = (__hip_bfloat16*)w; w += (size_t)B * RC * 2;
    __hip_bfloat16* hb0  = (__hip_bfloat16*)w; w += (size_t)B * H * 2;
    __hip_bfloat16* hb1  = (__hip_bfloat16*)w; w += (size_t)B * H * 2;
    __hip_bfloat16* tmp_h = (__hip_bfloat16*)w; w += (size_t)KW * B * H * 2;
    float* biasg  = (float*)w; w += (size_t)NG * 4;
    float* wrowg  = (float*)w; w += (size_t)NG * 4;
    float* bias16 = (float*)w; w += 64;
    float* wrow16 = (float*)w; w += 64;
    float* tmp_ds = (float*)w; w += (size_t)KW * B * 4;
    float* mean_h = (float*)w; w += (size_t)B * H * 4;
    float* t1     = (float*)w; w += (size_t)B * HS * 4;
    float* theme  = (float*)w; w += (size_t)B * H * 4;
    float* Pbuf   = (float*)w; w += (size_t)KS * B * H * 4;
    float* tmeT   = (float*)w; w += (size_t)T * B * 4;
    unsigned* bar = (unsigned*)w; w += 4096;

    hipMemsetAsync(hb0, 0, (size_t)B * H * sizeof(__hip_bfloat16), stream);
    hipMemsetAsync(bar, 0, 4096, stream);

    prep_wgt<<<dim3(NG / 64, KIN / 64), 256, 0, stream>>>(Wk, Wr, WgT);
    prep_w16rep<<<(16 * 16 * KIN + 255) / 256, 256, 0, stream>>>(Wk, Wr, WgT);
    prep_small<<<1, 256, 0, stream>>>(Wk, bk, Wr, br, biasg, wrowg, bias16, wrow16);
    convert_x<<<((B * T * F / 4) + 255) / 256, 256, 0, stream>>>(x, xb);
    prep_convw<<<((H * RC / 4) + 255) / 256, 256, 0, stream>>>(conv_w, CWb);
    prep_tmet<<<dim3(B / 32, T / 32), 256, 0, stream>>>(tme, tmeT);

    {
        StepArgs sa;
        sa.xb = xb; sa.h0 = hb0; sa.h1 = hb1; sa.WgT = WgT;
        sa.biasg = biasg; sa.wrowg = wrowg; sa.bias16 = bias16; sa.wrow16 = wrow16;
        sa.tmeT = tmeT; sa.tmp_h = tmp_h; sa.tmp_ds = tmp_ds; sa.dist_out = dist_out;
        sa.bar = bar;
        persistent_step<<<256, 512, 0, stream>>>(sa);
    }

    post_local<<<B, 128, 0, stream>>>(tmp_h, tmp_ds, mean_h, Ahk);
    theme1_k<<<(B * HS + 255) / 256, 256, 0, stream>>>(mean_h, Ws, bs, t1);
    theme2_k<<<(B * H + 255) / 256, 256, 0, stream>>>(t1, Wrs, brs, theme);
    conv_split<<<dim3(H / 128, B / 128, KS), 256, 0, stream>>>(Ahk, CWb, Pbuf);
    conv_reduce<<<(B * H + 255) / 256, 256, 0, stream>>>(Pbuf, conv_b, theme, out0);
}

// Round 4
// 2585.599 us; speedup vs baseline: 1.2494x; 1.2494x over previous
//
#include <hip/hip_runtime.h>
#include <hip/hip_bf16.h>
#include <cstddef>
#include <cstdint>

namespace {

constexpr int B = 2048, T = 128, F = 128, H = 512, L = 8, KW = 10;
constexpr int GATES = 2064;
constexpr int NG = 2048;    // gate columns (permuted)
constexpr int KIN = 640;    // F + H
constexpr int HS = 85;      // H // 6
constexpr int RC = H * KW;  // 5120
constexpr int KS = 8;       // conv split-K slices
constexpr int NROW = 144;   // WgT rows per tile: 128 gates + 16 logit cols

// LDS layout for persistent_step (exactly 160 KiB, 1 block/CU):
constexpr int ABUF2 = 0;        // A dbuf 2 x 16384 (phase = 2 k-slices)
constexpr int BRES2 = 32768;    // resident B slices 0..9 (10 x 8192)
constexpr int BRING = 114688;   // ring: 3 bufs x 16384 (phases 5..9)
// epilogue scratch aliases ring bufs (dead windows verified):
constexpr int LOGO  = 114688;   // logitS 128*17*4 = 8704
constexpr int DTSO2 = 123392;   // dts 512
constexpr int FMIMO = 123904;   // fmim 128*2*4 = 1024
constexpr int HSTO  = 124928;   // hstage 8192
constexpr int SMEM_SZ = 163840;

typedef __attribute__((ext_vector_type(8))) short short8;
typedef __attribute__((ext_vector_type(4))) float f32x4;
typedef unsigned long long ull;

__device__ __forceinline__ float fsigmoid_(float x) {
    return __builtin_amdgcn_rcpf(1.0f + __expf(-x));
}
__device__ __forceinline__ float ftanh_(float x) {
    return 1.0f - 2.0f * __builtin_amdgcn_rcpf(1.0f + __expf(2.0f * x));
}

__device__ __forceinline__ void gl_lds16(const void* g, void* l) {
    __builtin_amdgcn_global_load_lds(
        (const __attribute__((address_space(1))) unsigned int*)g,
        (__attribute__((address_space(3))) unsigned int*)l,
        16, 0, 0);
}

__device__ __forceinline__ ull h_atomic_load(const void* p) {
    return __hip_atomic_load((const ull*)p, __ATOMIC_RELAXED, __HIP_MEMORY_SCOPE_AGENT);
}

// ---------- prep (unchanged) ----------
__global__ __launch_bounds__(256) void prep_wgt(
    const float* __restrict__ Wk, const float* __restrict__ Wr,
    __hip_bfloat16* __restrict__ WgT)
{
    __shared__ float tile[64 * 65];
    const int tid = threadIdx.x;
    const int c0 = blockIdx.x * 64, k0 = blockIdx.y * 64;
#pragma unroll
    for (int rep = 0; rep < 16; ++rep) {
        int e = rep * 256 + tid;
        int kl = e >> 6, cl = e & 63;
        int col = c0 + cl;
        int nt = col >> 7, cc = col & 127;
        int n = 16 + ((cc >> 4) & 3) * 512 + nt * 32 + ((cc >> 6) & 1) * 16 + (cc & 15);
        int k = k0 + kl;
        tile[kl * 65 + cl] = (k < F) ? Wk[(size_t)k * GATES + n] : Wr[(size_t)(k - F) * GATES + n];
    }
    __syncthreads();
    const int cl = tid >> 2, q = tid & 3;
    unsigned short buf[16];
#pragma unroll
    for (int i = 0; i < 16; ++i) {
        float f = tile[(q * 16 + i) * 65 + cl];
        __hip_bfloat16 bv = __float2bfloat16(f);
        buf[i] = *(unsigned short*)&bv;
    }
    int col = c0 + cl;
    int nt = col >> 7, rin = col & 127;
    unsigned short* dst = (unsigned short*)WgT + (size_t)nt * NROW * KIN + (size_t)rin * KIN + k0 + q * 16;
    *(short8*)dst = *(short8*)&buf[0];
    *(short8*)(dst + 8) = *(short8*)&buf[8];
}

__global__ void prep_w16rep(const float* __restrict__ Wk, const float* __restrict__ Wr,
                            __hip_bfloat16* __restrict__ WgT)
{
    int idx = blockIdx.x * blockDim.x + threadIdx.x;
    if (idx >= 16 * 16 * KIN) return;
    int nt = idx / (16 * KIN);
    int rem = idx % (16 * KIN);
    int n = rem / KIN, k = rem % KIN;
    float v = (k < F) ? Wk[(size_t)k * GATES + n] : Wr[(size_t)(k - F) * GATES + n];
    WgT[(size_t)nt * NROW * KIN + (size_t)(128 + n) * KIN + k] = __float2bfloat16(v);
}

__global__ void prep_small(const float* __restrict__ Wk, const float* __restrict__ bk,
                           const float* __restrict__ Wr, const float* __restrict__ br,
                           float* __restrict__ biasg, float* __restrict__ wrowg,
                           float* __restrict__ bias16, float* __restrict__ wrow16)
{
    const int total = 2 * NG + 32;
    for (int idx = threadIdx.x; idx < total; idx += 256) {
        if (idx < NG) {
            int col = idx;
            int nt = col >> 7, cc = col & 127;
            int n = 16 + ((cc >> 4) & 3) * 512 + nt * 32 + ((cc >> 6) & 1) * 16 + (cc & 15);
            biasg[col] = bk[n] + br[n];
        } else if (idx < 2 * NG) {
            int col = idx - NG;
            int nt = col >> 7, cc = col & 127;
            int n = 16 + ((cc >> 4) & 3) * 512 + nt * 32 + ((cc >> 6) & 1) * 16 + (cc & 15);
            wrowg[col] = Wk[(size_t)F * GATES + n] + Wr[(size_t)H * GATES + n];
        } else if (idx < 2 * NG + 16) {
            int n = idx - 2 * NG;
            bias16[n] = bk[n] + br[n];
        } else {
            int n = idx - 2 * NG - 16;
            wrow16[n] = Wk[(size_t)F * GATES + n] + Wr[(size_t)H * GATES + n];
        }
    }
}

__global__ void convert_x(const float* __restrict__ x, __hip_bfloat16* __restrict__ xb) {
    int i = blockIdx.x * blockDim.x + threadIdx.x;
    size_t o = (size_t)i * 4;
    if (o >= (size_t)B * T * F) return;
    float4 v = *(const float4*)(x + o);
    xb[o + 0] = __float2bfloat16(v.x);
    xb[o + 1] = __float2bfloat16(v.y);
    xb[o + 2] = __float2bfloat16(v.z);
    xb[o + 3] = __float2bfloat16(v.w);
}

__global__ void prep_convw(const float* __restrict__ conv_w, __hip_bfloat16* __restrict__ CWb) {
    int i = blockIdx.x * blockDim.x + threadIdx.x;
    if (i >= H * RC / 4) return;
    size_t o = (size_t)i * 4;
    float4 v = *(const float4*)(conv_w + o);
    CWb[o + 0] = __float2bfloat16(v.x);
    CWb[o + 1] = __float2bfloat16(v.y);
    CWb[o + 2] = __float2bfloat16(v.z);
    CWb[o + 3] = __float2bfloat16(v.w);
}

// tme [B,T] -> tmeT [T,B]
__global__ __launch_bounds__(256) void prep_tmet(const float* __restrict__ tin,
                                                 float* __restrict__ tout)
{
    __shared__ float tl[32][33];
    const int bb = blockIdx.x * 32, tt = blockIdx.y * 32;
    const int tx = threadIdx.x & 31, ty = threadIdx.x >> 5;
#pragma unroll
    for (int r = 0; r < 32; r += 8)
        tl[ty + r][tx] = tin[(size_t)(bb + ty + r) * T + tt + tx];
    __syncthreads();
#pragma unroll
    for (int r = 0; r < 32; r += 8)
        tout[(size_t)(tt + ty + r) * B + bb + tx] = tl[tx][ty + r];
}

// ---------- persistent fused step ----------
struct StepArgs {
    const __hip_bfloat16* xb;
    __hip_bfloat16* h0;
    __hip_bfloat16* h1;
    const __hip_bfloat16* WgT;
    const float* biasg;
    const float* wrowg;
    const float* bias16;
    const float* wrow16;
    const float* tmeT;   // [T, B]
    __hip_bfloat16* tmp_h;
    float* tmp_ds;
    float* dist_out;
    unsigned* bar;  // flags[mt*16+nt]: producer step counter
};

// 256 blocks (16 mt x 16 nt, XCD-swizzled), 512 threads.
// R12: R2 skeleton at BK=64 granularity. 10 phases x 2 k-slices; A dbuf
// 2x16KB staged from regs; B = 10 resident slices + 3-buf ring staged 2
// phases ahead (counted vmcnt only at phases 5..9). Logit-B in wc0 VGPRs.
// Monolithic inter-step spin replaced by per-producer flags polled 4-at-a-
// time just before the phases that consume those h columns (straggler skew
// overlaps the consumer's epilogue + early phases). WAR on h dbuf closed by
// the one-step flag lag. 10 k-loop barriers/step (was 20).
__global__ __launch_bounds__(512, 2) void persistent_step(StepArgs a)
{
    __shared__ __align__(16) char smem[SMEM_SZ];
    float* logitS = (float*)(smem + LOGO);
    float* fmimS  = (float*)(smem + FMIMO);
    unsigned short* hstageS = (unsigned short*)(smem + HSTO);
    float* dts = (float*)(smem + DTSO2);

    const int tid = threadIdx.x;
    const int wave = tid >> 6;
    const int wr = wave >> 1, wc = wave & 1;   // wr 0..3, wc 0..1
    const int quad = (tid & 63) >> 4, m16 = tid & 15;
    const int l = blockIdx.x;
    const int nt = ((l & 7) << 1) | ((l >> 3) & 1);  // same-nt -> same XCD
    const int mt = l >> 4;
    const int m0 = mt * 128;
    const int lidx = nt >> 1;   // block-constant chunk index

    // ---- staging geometry (per k-slice: 128 rows x 32 k = 8 KB, 16 B/thread)
    const int o0 = tid * 16;
    const int arow = o0 >> 6;                       // 64 B per row-slice
    const int asl = ((((o0 >> 4) & 3) ^ ((arow >> 1) & 3)) << 3);  // k-elt slot
    const char* xbT = (const char*)a.xb + (size_t)(m0 + arow) * (T * F * 2) + asl * 2;
    const size_t hbyte = (size_t)(m0 + arow) * (H * 2) + asl * 2;
    const unsigned short* wgt_tile = (const unsigned short*)a.WgT + (size_t)nt * NROW * KIN;
    const int brow0 = o0 >> 6;
    const int bsl0 = ((((o0 >> 4) & 3) ^ ((brow0 >> 1) & 3)) << 3);
    const char* bsT0 = (const char*)(wgt_tile + (size_t)brow0 * KIN + bsl0);

    // ---- logit-B resident in VGPRs (wc==0 waves), t-invariant
    ull wv20[20][2];
    if (wc == 0) {
        const unsigned short* lrow = wgt_tile + (size_t)(128 + m16) * KIN + quad * 8;
#pragma unroll
        for (int s = 0; s < 20; ++s) {
            wv20[s][0] = *(const ull*)(lrow + s * 32);
            wv20[s][1] = *(const ull*)(lrow + s * 32 + 4);
        }
    }

    // ---- t-invariant epilogue constants
    const int hcol = nt * 32 + wc * 16 + m16;
    float bj[4], wj[4];
#pragma unroll
    for (int j = 0; j < 4; ++j) {
        int col = nt * 128 + wc * 64 + j * 16 + m16;
        bj[j] = a.biasg[col];
        wj[j] = a.wrowg[col];
    }
    const int soff = (tid >= 128 && tid < 256) ? 8 : 0;
    float b16r8[8], w16r8[8];
#pragma unroll
    for (int n = 0; n < 8; ++n) { b16r8[n] = a.bias16[soff + n]; w16r8[n] = a.wrow16[soff + n]; }

    float creg[2][4] = {};
    ull areg[2][4];   // [phase parity][2 slices x 2 halves]

    // ---- prologue: resident B 0..9; A phase-0 (t=0 slices 0,1); x aregs 2,3
    {
#pragma unroll
        for (int s = 0; s < 10; ++s)
            gl_lds16(bsT0 + s * 64, smem + BRES2 + s * 8192 + o0);
        gl_lds16(xbT, smem + ABUF2 + o0);
        gl_lds16(xbT + 64, smem + ABUF2 + 8192 + o0);
        areg[1][0] = *(const ull*)(xbT + 128);
        areg[1][1] = *(const ull*)(xbT + 136);
        areg[1][2] = *(const ull*)(xbT + 192);
        areg[1][3] = *(const ull*)(xbT + 200);
    }
    __syncthreads();  // drain prologue staging

#pragma unroll 1
    for (int t = 0; t < T; ++t) {
        const char* hs = (const char*)((t & 1) ? a.h1 : a.h0) + hbyte;
        unsigned* hout32 = (unsigned*)((t & 1) ? a.h0 : a.h1);

        float dtreg = 0.f;
        if (tid < 128) dtreg = a.tmeT[(size_t)t * B + m0 + tid];

        f32x4 acc[2][4] = {};
        f32x4 acc16[2] = {};

        // ---- 10-phase k-loop (phase q = slices 2q, 2q+1)
#pragma unroll
        for (int q = 0; q < 10; ++q) {
            // Barrier + wait policy: phases 1..4 read resident B / reg-staged
            // A only -> lgkmcnt(0). Phases 5..8: ring buf staged at q-2; ops
            // issued after it: (q-2) aregs 4 + (q-1) DMA 2 + aregs 4 = 10.
            // Phase 9: after its buf (staged q=7): aregs 4 only.
            if (q > 0) {
                if (q <= 4)      asm volatile("s_waitcnt lgkmcnt(0)" ::: "memory");
                else if (q <= 8) asm volatile("s_waitcnt vmcnt(10) lgkmcnt(0)" ::: "memory");
                else             asm volatile("s_waitcnt vmcnt(4) lgkmcnt(0)" ::: "memory");
                __builtin_amdgcn_s_barrier();
                __builtin_amdgcn_sched_barrier(0);
            }
            // stage A(q+1) from regs (slices 2q+2, 2q+3)
            if (q < 9) {
                char* ad = smem + ABUF2 + ((q + 1) & 1) * 16384;
                *(ull*)(ad + o0) = areg[(q + 1) & 1][0];
                *(ull*)(ad + o0 + 8) = areg[(q + 1) & 1][1];
                *(ull*)(ad + 8192 + o0) = areg[(q + 1) & 1][2];
                *(ull*)(ad + 8192 + o0 + 8) = areg[(q + 1) & 1][3];
            }
            // ring staging 2 phases ahead: q=3..7 stage slices 2q+4, 2q+5
            if (q >= 3 && q <= 7) {
                char* bb = smem + BRING + ((q - 3) % 3) * 16384;
                gl_lds16(bsT0 + (2 * q + 4) * 64, bb + o0);
                gl_lds16(bsT0 + (2 * q + 5) * 64, bb + 8192 + o0);
            }
            __builtin_amdgcn_sched_barrier(0);  // pin DMA before reloads
            // areg reload for phase q+2 (h slices 2q+4, 2q+5; all h since q>=0)
            if (q < 8) {
                const size_t ko = (size_t)(2 * q + 4) * 64 - 256;
                areg[q & 1][0] = h_atomic_load(hs + ko);
                areg[q & 1][1] = h_atomic_load(hs + ko + 8);
                areg[q & 1][2] = h_atomic_load(hs + ko + 64);
                areg[q & 1][3] = h_atomic_load(hs + ko + 72);
            }
            __builtin_amdgcn_sched_barrier(0);  // pin reloads before frag reads
            // compute phase q
            const unsigned short* Aq = (const unsigned short*)(smem + ABUF2 + (q & 1) * 16384);
#pragma unroll
            for (int ss = 0; ss < 2; ++ss) {
                const int s = 2 * q + ss;
                const unsigned short* A = Aq + ss * 4096;
                const unsigned short* Bb = (const unsigned short*)(smem +
                    (s < 10 ? BRES2 + s * 8192
                            : BRING + ((q - 5) % 3) * 16384 + ss * 8192));
                short8 av0, av1, bvv[4];
                {
                    const int ar0 = wr * 32 + m16;
                    av0 = *(const short8*)&A[ar0 * 32 + ((quad ^ ((ar0 >> 1) & 3)) << 3)];
                    const int ar1 = ar0 + 16;
                    av1 = *(const short8*)&A[ar1 * 32 + ((quad ^ ((ar1 >> 1) & 3)) << 3)];
                }
#pragma unroll
                for (int j = 0; j < 4; ++j) {
                    int br = wc * 64 + j * 16 + m16;
                    bvv[j] = *(const short8*)&Bb[br * 32 + ((quad ^ ((br >> 1) & 3)) << 3)];
                }
#pragma unroll
                for (int j = 0; j < 4; ++j) {
                    acc[0][j] = __builtin_amdgcn_mfma_f32_16x16x32_bf16(av0, bvv[j], acc[0][j], 0, 0, 0);
                    acc[1][j] = __builtin_amdgcn_mfma_f32_16x16x32_bf16(av1, bvv[j], acc[1][j], 0, 0, 0);
                }
                if (wc == 0) {
                    short8 wv;
                    ((ull*)&wv)[0] = wv20[s][0]; ((ull*)&wv)[1] = wv20[s][1];
                    acc16[0] = __builtin_amdgcn_mfma_f32_16x16x32_bf16(av0, wv, acc16[0], 0, 0, 0);
                    acc16[1] = __builtin_amdgcn_mfma_f32_16x16x32_bf16(av1, wv, acc16[1], 0, 0, 0);
                }
            }
            // fine-grained producer polls: tail of q gates phases q+1,q+2
            // reloads (producers 2q+2 .. 2q+5)
            if ((q == 1 || q == 3 || q == 5) && t > 0) {
                if (tid == 0) {
                    const unsigned tgt = (unsigned)t;
                    const unsigned* f = a.bar + mt * 16 + 2 * q + 2;
#pragma unroll
                    for (int j = 0; j < 4; ++j) {
                        for (int it = 0; it < (1 << 22); ++it) {
                            if (__hip_atomic_load(f + j, __ATOMIC_RELAXED,
                                                  __HIP_MEMORY_SCOPE_AGENT) >= tgt) break;
                            __builtin_amdgcn_s_sleep(1);
                        }
                    }
                }
            }
        }
        __syncthreads();  // k-loop done; ring scratch safe to alias

        // logits + dts -> LDS
        if (tid < 128) dts[tid] = dtreg;
        if (wc == 0) {
#pragma unroll
            for (int i = 0; i < 2; ++i)
#pragma unroll
                for (int r = 0; r < 4; ++r)
                    logitS[(wr * 32 + i * 16 + quad * 4 + r) * 17 + m16] = acc16[i][r];
        }
        __syncthreads();

        // per-row softmax-cumsum: fm half tid<128, im half tid 128..255
        if (tid < 256) {
            const int row = tid & 127;
            const int m = m0 + row;
            const bool hi = tid >= 128;
            const float dt = hi ? dts[row] : dtreg;
            float z[8];
#pragma unroll
            for (int n = 0; n < 8; ++n)
                z[n] = logitS[row * 17 + soff + n] + b16r8[n] + dt * w16r8[n];
            float mx = z[0];
#pragma unroll
            for (int j = 1; j < 8; ++j) mx = fmaxf(mx, z[j]);
            float e[8], s = 0.f;
#pragma unroll
            for (int j = 0; j < 8; ++j) { e[j] = __expf(z[j] - mx); s += e[j]; }
            const float inv = __builtin_amdgcn_rcpf(s);
            if (!hi) {
                float run = 0.f, fsum = 0.f, val = 0.f;
#pragma unroll
                for (int j = 0; j < 8; ++j) {
                    run += e[j];
                    float fmv = run * inv;
                    if (j == lidx) val = fmv;
                    fsum += fmv;
                }
                fmimS[row * 2] = val;
                if (nt == 0) {
                    float d = 1.0f - fsum * 0.125f;
                    a.dist_out[(size_t)t * B + m] = d;
                    if (t >= T - KW) a.tmp_ds[(size_t)(t - (T - KW)) * B + m] = d;
                }
            } else {
                float run = 0.f, val = 0.f;
#pragma unroll
                for (int j = 7; j >= 0; --j) {
                    run += e[j];
                    if (j == lidx) val = run * inv;
                }
                fmimS[row * 2 + 1] = val;
            }
        }
        __syncthreads();

        // gates + cell update (c in regs); h -> LDS stage
#pragma unroll
        for (int i = 0; i < 2; ++i) {
#pragma unroll
            for (int r = 0; r < 4; ++r) {
                int rl = wr * 32 + i * 16 + quad * 4 + r;
                int m = m0 + rl;
                float dt = dts[rl];
                float fmv = fmimS[rl * 2];
                float imv = fmimS[rl * 2 + 1];
                float fg = fsigmoid_(acc[i][0][r] + bj[0] + dt * wj[0]);
                float ig = fsigmoid_(acc[i][1][r] + bj[1] + dt * wj[1]);
                float og = fsigmoid_(acc[i][2][r] + bj[2] + dt * wj[2]);
                float ci = ftanh_(acc[i][3][r] + bj[3] + dt * wj[3]);
                float ov = fmv * imv;
                float cl = creg[i][r];
                float cn = ov * (fg * cl + ig * ci) + (fmv - ov) * cl + (imv - ov) * ci;
                float hn = og * ftanh_(cn);
                creg[i][r] = cn;
                __hip_bfloat16 hb = __float2bfloat16(hn);
                hstageS[rl * 32 + (wc * 16 + m16)] = *(unsigned short*)&hb;
                if (t >= T - KW) a.tmp_h[((size_t)(t - (T - KW)) * B + m) * H + hcol] = hb;
            }
        }
        __syncthreads();

        // pack h pairs -> agent-scope atomic dword stores
        {
            const unsigned* hs32 = (const unsigned*)hstageS;
#pragma unroll
            for (int wds = 0; wds < 4; ++wds) {
                int wi = wds * 512 + tid;
                int row = wi >> 4, cp = wi & 15;
                unsigned v = hs32[row * 16 + cp];
                __hip_atomic_store(hout32 + (size_t)(m0 + row) * (H / 2) + nt * 16 + cp, v,
                                   __ATOMIC_RELAXED, __HIP_MEMORY_SCOPE_AGENT);
            }
        }

        __syncthreads();  // pack reads done + all h stores drained (vmcnt0)
        if (t != T - 1) {
            // publish our h(t) ASAP, then pre-issue next step's phase-0 A DMA
            // + x aregs, then gate phases 0,1 on producers 0..3
            if (tid == 0)
                __hip_atomic_store(a.bar + (mt * 16 + nt), (unsigned)(t + 1),
                                   __ATOMIC_RELAXED, __HIP_MEMORY_SCOPE_AGENT);
            const char* xn = xbT + (size_t)(t + 1) * 256;
            gl_lds16(xn, smem + ABUF2 + o0);
            gl_lds16(xn + 64, smem + ABUF2 + 8192 + o0);
            areg[1][0] = *(const ull*)(xn + 128);
            areg[1][1] = *(const ull*)(xn + 136);
            areg[1][2] = *(const ull*)(xn + 192);
            areg[1][3] = *(const ull*)(xn + 200);
            if (tid == 0) {
                const unsigned tgt = (unsigned)(t + 1);
                const unsigned* f = a.bar + mt * 16;
#pragma unroll
                for (int j = 0; j < 4; ++j) {
                    for (int it = 0; it < (1 << 22); ++it) {
                        if (__hip_atomic_load(f + j, __ATOMIC_RELAXED,
                                              __HIP_MEMORY_SCOPE_AGENT) >= tgt) break;
                        __builtin_amdgcn_s_sleep(2);
                    }
                }
            }
            __syncthreads();  // releases block + drains pre-issued staging
        }
    }
}

// ---------- post (unchanged) ----------
__global__ __launch_bounds__(128) void post_local(
    const __hip_bfloat16* __restrict__ tmp_h, const float* __restrict__ tmp_dis,
    float* __restrict__ mean_h, __hip_bfloat16* __restrict__ Ahk)
{
    const int b = blockIdx.x;
    const int tid = threadIdx.x;
    __shared__ float ld[KW];
    if (tid == 0) {
        float cd[KW];
        float run = 0.f;
        for (int k = 0; k < KW; ++k) { run += tmp_dis[(size_t)k * B + b]; cd[k] = run; }
        float mx = cd[0];
        for (int k = 1; k < KW; ++k) mx = fmaxf(mx, cd[k]);
        float s = 0.f;
        for (int k = 0; k < KW; ++k) { cd[k] = expf(cd[k] - mx); s += cd[k]; }
        for (int k = 0; k < KW; ++k) ld[k] = cd[k] / s;
    }
    __syncthreads();
    float ldr[KW];
#pragma unroll
    for (int k = 0; k < KW; ++k) ldr[k] = ld[k];
    for (int h = tid; h < H; h += 128) {
        float s = 0.f;
#pragma unroll
        for (int k = 0; k < KW; ++k) {
            float v = __bfloat162float(tmp_h[((size_t)k * B + b) * H + h]) * ldr[k];
            s += v;
            Ahk[(size_t)b * RC + h * KW + k] = __float2bfloat16(v);
        }
        mean_h[(size_t)b * H + h] = s * (1.0f / KW);
    }
}

__global__ void theme1_k(const float* __restrict__ mean_h, const float* __restrict__ Ws,
                         const float* __restrict__ bs, float* __restrict__ t1)
{
    int idx = blockIdx.x * blockDim.x + threadIdx.x;
    if (idx >= B * HS) return;
    int b = idx / HS, j = idx % HS;
    float s = bs[j];
    const float* mh = mean_h + (size_t)b * H;
    for (int h = 0; h < H; ++h) s += mh[h] * Ws[(size_t)h * HS + j];
    t1[idx] = fmaxf(s, 0.f);
}

__global__ void theme2_k(const float* __restrict__ t1, const float* __restrict__ Wrs,
                         const float* __restrict__ brs, float* __restrict__ theme)
{
    int idx = blockIdx.x * blockDim.x + threadIdx.x;
    if (idx >= B * H) return;
    int b = idx / H, o = idx % H;
    float s = brs[o];
    const float* tv = t1 + (size_t)b * HS;
    for (int j = 0; j < HS; ++j) s += tv[j] * Wrs[(size_t)j * H + o];
    theme[idx] = 1.0f / (1.0f + expf(-s));
}

__global__ __launch_bounds__(256) void conv_split(
    const __hip_bfloat16* __restrict__ Ahk, const __hip_bfloat16* __restrict__ CWb,
    float* __restrict__ Pbuf)
{
    __shared__ __align__(16) unsigned short As2[128 * 64];
    __shared__ __align__(16) unsigned short Bs2[128 * 64];
    const int tid = threadIdx.x;
    const int wave = tid >> 6;
    const int wr = wave >> 1, wc = wave & 1;
    const int quad = (tid & 63) >> 4, m16 = tid & 15;
    const int n0 = blockIdx.x * 128, m0 = blockIdx.y * 128;
    const int ksb = blockIdx.z * (RC / KS);

    f32x4 acc[4][4] = {};
    for (int k0 = 0; k0 < RC / KS; k0 += 64) {
#pragma unroll
        for (int p = 0; p < 4; ++p) {
            int o = p * 4096 + tid * 16;
            int row = o >> 7, slot = (o >> 4) & 7;
            int kg = ksb + k0 + (slot ^ (row & 7)) * 8;
            gl_lds16((const unsigned short*)Ahk + (size_t)(m0 + row) * RC + kg, (char*)As2 + o);
            gl_lds16((const unsigned short*)CWb + (size_t)(n0 + row) * RC + kg, (char*)Bs2 + o);
        }
        __syncthreads();
#pragma unroll
        for (int c2 = 0; c2 < 2; ++c2) {
            const int k8 = c2 * 4 + quad;
            short8 av[4], bv[4];
#pragma unroll
            for (int i = 0; i < 4; ++i) {
                int arow2 = wr * 64 + i * 16 + m16;
                av[i] = *(const short8*)&As2[arow2 * 64 + (k8 ^ (arow2 & 7)) * 8];
            }
#pragma unroll
            for (int j = 0; j < 4; ++j) {
                int brow = wc * 64 + j * 16 + m16;
                bv[j] = *(const short8*)&Bs2[brow * 64 + (k8 ^ (brow & 7)) * 8];
            }
#pragma unroll
            for (int i = 0; i < 4; ++i)
#pragma unroll
                for (int j = 0; j < 4; ++j)
                    acc[i][j] = __builtin_amdgcn_mfma_f32_16x16x32_bf16(av[i], bv[j], acc[i][j], 0, 0, 0);
        }
        __syncthreads();
    }
    float* P = Pbuf + (size_t)blockIdx.z * B * H;
#pragma unroll
    for (int j = 0; j < 4; ++j) {
        const int col = n0 + wc * 64 + j * 16 + m16;
#pragma unroll
        for (int i = 0; i < 4; ++i) {
            const int rb = m0 + wr * 64 + i * 16 + quad * 4;
#pragma unroll
            for (int r = 0; r < 4; ++r)
                P[(size_t)(rb + r) * H + col] = acc[i][j][r];
        }
    }
}

__global__ void conv_reduce(const float* __restrict__ Pbuf, const float* __restrict__ conv_b,
                            const float* __restrict__ theme, float* __restrict__ out0)
{
    int i = blockIdx.x * blockDim.x + threadIdx.x;
    if (i >= B * H) return;
    float s = conv_b[i & (H - 1)];
#pragma unroll
    for (int ks = 0; ks < KS; ++ks) s += Pbuf[(size_t)ks * B * H + i];
    out0[i] = theme[i] * s;
}

} // namespace

extern "C" void kernel_launch(void* const* d_in, const int* in_sizes, int n_in,
                              void* d_out, int out_size, void* d_ws, size_t ws_size,
                              hipStream_t stream)
{
    (void)in_sizes; (void)n_in; (void)out_size; (void)ws_size;
    const float* x      = (const float*)d_in[0];
    const float* tme    = (const float*)d_in[1];
    const float* Wk     = (const float*)d_in[2];
    const float* bk     = (const float*)d_in[3];
    const float* Wr     = (const float*)d_in[4];
    const float* br     = (const float*)d_in[5];
    const float* Ws     = (const float*)d_in[6];
    const float* bs     = (const float*)d_in[7];
    const float* Wrs    = (const float*)d_in[8];
    const float* brs    = (const float*)d_in[9];
    const float* conv_w = (const float*)d_in[10];
    const float* conv_b = (const float*)d_in[11];

    float* out0 = (float*)d_out;
    float* dist_out = out0 + (size_t)B * H;

    // workspace carve (~163 MB)
    char* w = (char*)d_ws;
    __hip_bfloat16* WgT  = (__hip_bfloat16*)w; w += (size_t)16 * NROW * KIN * 2;
    __hip_bfloat16* xb   = (__hip_bfloat16*)w; w += (size_t)B * T * F * 2;
    __hip_bfloat16* CWb  = (__hip_bfloat16*)w; w += (size_t)H * RC * 2;
    __hip_bfloat16* Ahk  = (__hip_bfloat16*)w; w += (size_t)B * RC * 2;
    __hip_bfloat16* hb0  = (__hip_bfloat16*)w; w += (size_t)B * H * 2;
    __hip_bfloat16* hb1  = (__hip_bfloat16*)w; w += (size_t)B * H * 2;
    __hip_bfloat16* tmp_h = (__hip_bfloat16*)w; w += (size_t)KW * B * H * 2;
    float* biasg  = (float*)w; w += (size_t)NG * 4;
    float* wrowg  = (float*)w; w += (size_t)NG * 4;
    float* bias16 = (float*)w; w += 64;
    float* wrow16 = (float*)w; w += 64;
    float* tmp_ds = (float*)w; w += (size_t)KW * B * 4;
    float* mean_h = (float*)w; w += (size_t)B * H * 4;
    float* t1     = (float*)w; w += (size_t)B * HS * 4;
    float* theme  = (float*)w; w += (size_t)B * H * 4;
    float* Pbuf   = (float*)w; w += (size_t)KS * B * H * 4;
    float* tmeT   = (float*)w; w += (size_t)T * B * 4;
    unsigned* bar = (unsigned*)w; w += 4096;

    hipMemsetAsync(hb0, 0, (size_t)B * H * sizeof(__hip_bfloat16), stream);
    hipMemsetAsync(bar, 0, 4096, stream);

    prep_wgt<<<dim3(NG / 64, KIN / 64), 256, 0, stream>>>(Wk, Wr, WgT);
    prep_w16rep<<<(16 * 16 * KIN + 255) / 256, 256, 0, stream>>>(Wk, Wr, WgT);
    prep_small<<<1, 256, 0, stream>>>(Wk, bk, Wr, br, biasg, wrowg, bias16, wrow16);
    convert_x<<<((B * T * F / 4) + 255) / 256, 256, 0, stream>>>(x, xb);
    prep_convw<<<((H * RC / 4) + 255) / 256, 256, 0, stream>>>(conv_w, CWb);
    prep_tmet<<<dim3(B / 32, T / 32), 256, 0, stream>>>(tme, tmeT);

    {
        StepArgs sa;
        sa.xb = xb; sa.h0 = hb0; sa.h1 = hb1; sa.WgT = WgT;
        sa.biasg = biasg; sa.wrowg = wrowg; sa.bias16 = bias16; sa.wrow16 = wrow16;
        sa.tmeT = tmeT; sa.tmp_h = tmp_h; sa.tmp_ds = tmp_ds; sa.dist_out = dist_out;
        sa.bar = bar;
        persistent_step<<<256, 512, 0, stream>>>(sa);
    }

    post_local<<<B, 128, 0, stream>>>(tmp_h, tmp_ds, mean_h, Ahk);
    theme1_k<<<(B * HS + 255) / 256, 256, 0, stream>>>(mean_h, Ws, bs, t1);
    theme2_k<<<(B * H + 255) / 256, 256, 0, stream>>>(t1, Wrs, brs, theme);
    conv_split<<<dim3(H / 128, B / 128, KS), 256, 0, stream>>>(Ahk, CWb, Pbuf);
    conv_reduce<<<(B * H + 255) / 256, 256, 0, stream>>>(Pbuf, conv_b, theme, out0);
}

// Round 5
// 2354.345 us; speedup vs baseline: 1.3721x; 1.0982x over previous
//
#include <hip/hip_runtime.h>
#include <hip/hip_bf16.h>
#include <cstddef>
#include <cstdint>

namespace {

constexpr int B = 2048, T = 128, F = 128, H = 512, L = 8, KW = 10;
constexpr int GATES = 2064;
constexpr int NG = 2048;    // gate columns (permuted)
constexpr int KIN = 640;    // F + H
constexpr int HS = 85;      // H // 6
constexpr int RC = H * KW;  // 5120
constexpr int KS = 8;       // conv split-K slices
constexpr int NROW = 144;   // WgT rows per tile: 128 gates + 16 logit cols

// LDS layout for persistent_step (exactly 160 KiB, 1 block/CU):
constexpr int BSLICE = 8192;     // one B k-slice: 128 rows x 32 k bf16
constexpr int ABUF = 0;          // A double buffer 2 x 8192
constexpr int BRES = 16384;      // resident B slices 0..14 (15 x 8192)
constexpr int BRING = 139264;    // ring: 3 x 8192 (slices 15..19, staged ki-2)
// epilogue scratch aliases the ring (all windows dead before next-step ki>=13):
constexpr int LOGO  = 139264;    // logitS 128*17*4 = 8704
constexpr int DTSO  = 147968;    // dts 512
constexpr int FMIMO = 148480;    // fmim 128*2*4 = 1024
constexpr int HSTO  = 149504;    // hstage 8192 (ends 157696)
constexpr int SMEM_SZ = 163840;

typedef __attribute__((ext_vector_type(8))) short short8;
typedef __attribute__((ext_vector_type(4))) float f32x4;
typedef unsigned long long ull;

__device__ __forceinline__ float fsigmoid_(float x) {
    return __builtin_amdgcn_rcpf(1.0f + __expf(-x));
}
__device__ __forceinline__ float ftanh_(float x) {
    return 1.0f - 2.0f * __builtin_amdgcn_rcpf(1.0f + __expf(2.0f * x));
}

__device__ __forceinline__ void gl_lds16(const void* g, void* l) {
    __builtin_amdgcn_global_load_lds(
        (const __attribute__((address_space(1))) unsigned int*)g,
        (__attribute__((address_space(3))) unsigned int*)l,
        16, 0, 0);
}

__device__ __forceinline__ ull h_atomic_load(const void* p) {
    return __hip_atomic_load((const ull*)p, __ATOMIC_RELAXED, __HIP_MEMORY_SCOPE_AGENT);
}

// ---------- prep (unchanged) ----------
__global__ __launch_bounds__(256) void prep_wgt(
    const float* __restrict__ Wk, const float* __restrict__ Wr,
    __hip_bfloat16* __restrict__ WgT)
{
    __shared__ float tile[64 * 65];
    const int tid = threadIdx.x;
    const int c0 = blockIdx.x * 64, k0 = blockIdx.y * 64;
#pragma unroll
    for (int rep = 0; rep < 16; ++rep) {
        int e = rep * 256 + tid;
        int kl = e >> 6, cl = e & 63;
        int col = c0 + cl;
        int nt = col >> 7, cc = col & 127;
        int n = 16 + ((cc >> 4) & 3) * 512 + nt * 32 + ((cc >> 6) & 1) * 16 + (cc & 15);
        int k = k0 + kl;
        tile[kl * 65 + cl] = (k < F) ? Wk[(size_t)k * GATES + n] : Wr[(size_t)(k - F) * GATES + n];
    }
    __syncthreads();
    const int cl = tid >> 2, q = tid & 3;
    unsigned short buf[16];
#pragma unroll
    for (int i = 0; i < 16; ++i) {
        float f = tile[(q * 16 + i) * 65 + cl];
        __hip_bfloat16 bv = __float2bfloat16(f);
        buf[i] = *(unsigned short*)&bv;
    }
    int col = c0 + cl;
    int nt = col >> 7, rin = col & 127;
    unsigned short* dst = (unsigned short*)WgT + (size_t)nt * NROW * KIN + (size_t)rin * KIN + k0 + q * 16;
    *(short8*)dst = *(short8*)&buf[0];
    *(short8*)(dst + 8) = *(short8*)&buf[8];
}

__global__ void prep_w16rep(const float* __restrict__ Wk, const float* __restrict__ Wr,
                            __hip_bfloat16* __restrict__ WgT)
{
    int idx = blockIdx.x * blockDim.x + threadIdx.x;
    if (idx >= 16 * 16 * KIN) return;
    int nt = idx / (16 * KIN);
    int rem = idx % (16 * KIN);
    int n = rem / KIN, k = rem % KIN;
    float v = (k < F) ? Wk[(size_t)k * GATES + n] : Wr[(size_t)(k - F) * GATES + n];
    WgT[(size_t)nt * NROW * KIN + (size_t)(128 + n) * KIN + k] = __float2bfloat16(v);
}

__global__ void prep_small(const float* __restrict__ Wk, const float* __restrict__ bk,
                           const float* __restrict__ Wr, const float* __restrict__ br,
                           float* __restrict__ biasg, float* __restrict__ wrowg,
                           float* __restrict__ bias16, float* __restrict__ wrow16)
{
    const int total = 2 * NG + 32;
    for (int idx = threadIdx.x; idx < total; idx += 256) {
        if (idx < NG) {
            int col = idx;
            int nt = col >> 7, cc = col & 127;
            int n = 16 + ((cc >> 4) & 3) * 512 + nt * 32 + ((cc >> 6) & 1) * 16 + (cc & 15);
            biasg[col] = bk[n] + br[n];
        } else if (idx < 2 * NG) {
            int col = idx - NG;
            int nt = col >> 7, cc = col & 127;
            int n = 16 + ((cc >> 4) & 3) * 512 + nt * 32 + ((cc >> 6) & 1) * 16 + (cc & 15);
            wrowg[col] = Wk[(size_t)F * GATES + n] + Wr[(size_t)H * GATES + n];
        } else if (idx < 2 * NG + 16) {
            int n = idx - 2 * NG;
            bias16[n] = bk[n] + br[n];
        } else {
            int n = idx - 2 * NG - 16;
            wrow16[n] = Wk[(size_t)F * GATES + n] + Wr[(size_t)H * GATES + n];
        }
    }
}

__global__ void convert_x(const float* __restrict__ x, __hip_bfloat16* __restrict__ xb) {
    int i = blockIdx.x * blockDim.x + threadIdx.x;
    size_t o = (size_t)i * 4;
    if (o >= (size_t)B * T * F) return;
    float4 v = *(const float4*)(x + o);
    xb[o + 0] = __float2bfloat16(v.x);
    xb[o + 1] = __float2bfloat16(v.y);
    xb[o + 2] = __float2bfloat16(v.z);
    xb[o + 3] = __float2bfloat16(v.w);
}

__global__ void prep_convw(const float* __restrict__ conv_w, __hip_bfloat16* __restrict__ CWb) {
    int i = blockIdx.x * blockDim.x + threadIdx.x;
    if (i >= H * RC / 4) return;
    size_t o = (size_t)i * 4;
    float4 v = *(const float4*)(conv_w + o);
    CWb[o + 0] = __float2bfloat16(v.x);
    CWb[o + 1] = __float2bfloat16(v.y);
    CWb[o + 2] = __float2bfloat16(v.z);
    CWb[o + 3] = __float2bfloat16(v.w);
}

// tme [B,T] -> tmeT [T,B]
__global__ __launch_bounds__(256) void prep_tmet(const float* __restrict__ tin,
                                                 float* __restrict__ tout)
{
    __shared__ float tl[32][33];
    const int bb = blockIdx.x * 32, tt = blockIdx.y * 32;
    const int tx = threadIdx.x & 31, ty = threadIdx.x >> 5;
#pragma unroll
    for (int r = 0; r < 32; r += 8)
        tl[ty + r][tx] = tin[(size_t)(bb + ty + r) * T + tt + tx];
    __syncthreads();
#pragma unroll
    for (int r = 0; r < 32; r += 8)
        tout[(size_t)(tt + ty + r) * B + bb + tx] = tl[tx][ty + r];
}

// ---------- persistent fused step ----------
struct StepArgs {
    const __hip_bfloat16* xb;
    __hip_bfloat16* h0;
    __hip_bfloat16* h1;
    const __hip_bfloat16* WgT;
    const float* biasg;
    const float* wrowg;
    const float* bias16;
    const float* wrow16;
    const float* tmeT;   // [T, B]
    __hip_bfloat16* tmp_h;
    float* tmp_ds;
    float* dist_out;
    unsigned* bar;  // per-mt-group counters, 256 B apart
};

// 256 blocks (16 mt x 16 nt, XCD-swizzled), 512 threads.
// R13 = R2 skeleton (verified best) + 3 incremental deltas:
//  (1) logit-B (16x640) in wc0 VGPRs -> uniform 8KB slices, 1 DMA/slice/
//      thread, no per-iter wc0 LDS read, uniform vmcnt counts;
//  (2) 15 resident slices; ring only 15..19 (staged at ki-2); 15/20 iters
//      are lgkmcnt-only barriers; spin pre-issue = A(0)+x only;
//  (3) 2-float fmim (lidx = nt>>1 block-constant) + dtreg preload.
__global__ __launch_bounds__(512, 2) void persistent_step(StepArgs a)
{
    __shared__ __align__(16) char smem[SMEM_SZ];
    float* logitS = (float*)(smem + LOGO);
    float* fmimS  = (float*)(smem + FMIMO);
    unsigned short* hstageS = (unsigned short*)(smem + HSTO);
    float* dts = (float*)(smem + DTSO);

    const int tid = threadIdx.x;
    const int wave = tid >> 6;
    const int wr = wave >> 1, wc = wave & 1;   // wr 0..3, wc 0..1
    const int quad = (tid & 63) >> 4, m16 = tid & 15;
    const int l = blockIdx.x;
    const int nt = ((l & 7) << 1) | ((l >> 3) & 1);  // same-nt -> same XCD
    const int mt = l >> 4;
    const int m0 = mt * 128;
    const int lidx = nt >> 1;   // block-constant chunk index

    // ---- per-thread staging geometry (8 KB tile; 16 B/thread)
    const int o0 = tid * 16;
    const int arow = o0 >> 6;                       // 64 B per row
    const int asl = ((((o0 >> 4) & 3) ^ ((arow >> 1) & 3)) << 3);  // k-elt offset
    const char* xbT = (const char*)a.xb + (size_t)(m0 + arow) * (T * F * 2) + asl * 2;
    const size_t hbyte = (size_t)(m0 + arow) * (H * 2) + asl * 2;
    const unsigned short* wgt_tile = (const unsigned short*)a.WgT + (size_t)nt * NROW * KIN;
    const char* bsT0 = (const char*)(wgt_tile + (size_t)arow * KIN + asl);
    auto stageB = [&](int s, int off) {
        gl_lds16(bsT0 + s * 64, smem + off + o0);
    };

    // ---- logit-B resident in VGPRs (wc==0 waves), t-invariant
    ull wv20[20][2];
    if (wc == 0) {
        const unsigned short* lrow = wgt_tile + (size_t)(128 + m16) * KIN + quad * 8;
#pragma unroll
        for (int s = 0; s < 20; ++s) {
            wv20[s][0] = *(const ull*)(lrow + s * 32);
            wv20[s][1] = *(const ull*)(lrow + s * 32 + 4);
        }
    }

    // ---- t-invariant epilogue constants
    const int hcol = nt * 32 + wc * 16 + m16;
    float bj[4], wj[4];
#pragma unroll
    for (int j = 0; j < 4; ++j) {
        int col = nt * 128 + wc * 64 + j * 16 + m16;
        bj[j] = a.biasg[col];
        wj[j] = a.wrowg[col];
    }
    const int soff = (tid >= 128 && tid < 256) ? 8 : 0;
    float b16r8[8], w16r8[8];
#pragma unroll
    for (int n = 0; n < 8; ++n) { b16r8[n] = a.bias16[soff + n]; w16r8[n] = a.wrow16[soff + n]; }

    const unsigned short* Abase = (const unsigned short*)smem;

    float creg[2][4] = {};
    ull areg[2][2];

    // ---- prologue: stage resident B 0..14 once; A(0) DMA; x aregs iters 1,2
    {
#pragma unroll
        for (int s = 0; s < 15; ++s) stageB(s, BRES + s * BSLICE);
        gl_lds16(xbT, smem + o0);
        areg[1][0] = *(const ull*)(xbT + 64);  areg[1][1] = *(const ull*)(xbT + 72);
        areg[0][0] = *(const ull*)(xbT + 128); areg[0][1] = *(const ull*)(xbT + 136);
    }
    __syncthreads();  // drain prologue staging

#pragma unroll 1
    for (int t = 0; t < T; ++t) {
        const char* xt = xbT + (size_t)t * 256;
        const char* hs = (const char*)((t & 1) ? a.h1 : a.h0) + hbyte;
        unsigned* hout32 = (unsigned*)((t & 1) ? a.h0 : a.h1);

        float dtreg = 0.f;
        if (tid < 128) dtreg = a.tmeT[(size_t)t * B + m0 + tid];

        f32x4 acc[2][4] = {};
        f32x4 acc16[2] = {};

#pragma unroll
        for (int ki = 0; ki < 20; ++ki) {
            // Barrier + wait policy (uniform across waves; per-iter vmem issue
            // order is [B-DMA x1 (ki 13..17 stage slice ki+2)][h-reload x2]):
            //  ki 1..14 : B resident -> lgkmcnt(0) only (compiler handles
            //             areg register deps with its own vmcnt).
            //  ki 15..17: B(ki) DMA'd at ki-2; newer ops: h x2, B x1, h x2
            //             -> vmcnt(5).
            //  ki 18    : newer: h x2, B x1 -> vmcnt(3).
            //  ki 19    : nothing newer -> vmcnt(0).
            if (ki > 0) {
                if (ki <= 14)
                    asm volatile("s_waitcnt lgkmcnt(0)" ::: "memory");
                else if (ki <= 17)
                    asm volatile("s_waitcnt vmcnt(5) lgkmcnt(0)" ::: "memory");
                else if (ki == 18)
                    asm volatile("s_waitcnt vmcnt(3) lgkmcnt(0)" ::: "memory");
                else
                    asm volatile("s_waitcnt vmcnt(0) lgkmcnt(0)" ::: "memory");
                __builtin_amdgcn_s_barrier();
                __builtin_amdgcn_sched_barrier(0);
            }
            const int nxt = ki + 1;
            if (nxt < 20) {
                // stage A(nxt) from regs
                char* adst = smem + (nxt & 1) * 8192 + o0;
                *(ull*)adst = areg[nxt & 1][0];
                *(ull*)(adst + 8) = areg[nxt & 1][1];
            }
            // ring staging: ki 13..17 stage slice ki+2 -> buf (ki-13)%3
            if (ki >= 13 && ki <= 17) {
                stageB(ki + 2, BRING + ((ki - 13) % 3) * BSLICE);
            }
            __builtin_amdgcn_sched_barrier(0);  // pin DMA before reloads
            // reload areg set for iter ki+3
            const int fut = ki + 3;
            if (fut < 20) {
                if (fut <= 3) {
                    areg[fut & 1][0] = *(const ull*)(xt + fut * 64);
                    areg[fut & 1][1] = *(const ull*)(xt + fut * 64 + 8);
                } else {
                    areg[fut & 1][0] = h_atomic_load(hs + fut * 64 - 256);
                    areg[fut & 1][1] = h_atomic_load(hs + fut * 64 - 248);
                }
            }
            __builtin_amdgcn_sched_barrier(0);  // pin reloads before frag reads
            // compute iter ki
            const unsigned short* A = Abase + (ki & 1) * 4096;
            const unsigned short* Bb = (const unsigned short*)(smem +
                (ki < 15 ? BRES + ki * BSLICE : BRING + ((ki - 15) % 3) * BSLICE));
            short8 av[2], bv[4];
#pragma unroll
            for (int i = 0; i < 2; ++i) {
                int ar = wr * 32 + i * 16 + m16;
                av[i] = *(const short8*)&A[ar * 32 + ((quad ^ ((ar >> 1) & 3)) << 3)];
            }
#pragma unroll
            for (int j = 0; j < 4; ++j) {
                int br = wc * 64 + j * 16 + m16;
                bv[j] = *(const short8*)&Bb[br * 32 + ((quad ^ ((br >> 1) & 3)) << 3)];
            }
#pragma unroll
            for (int i = 0; i < 2; ++i)
#pragma unroll
                for (int j = 0; j < 4; ++j)
                    acc[i][j] = __builtin_amdgcn_mfma_f32_16x16x32_bf16(av[i], bv[j], acc[i][j], 0, 0, 0);
            if (wc == 0) {
                short8 wv;
                ((ull*)&wv)[0] = wv20[ki][0]; ((ull*)&wv)[1] = wv20[ki][1];
                acc16[0] = __builtin_amdgcn_mfma_f32_16x16x32_bf16(av[0], wv, acc16[0], 0, 0, 0);
                acc16[1] = __builtin_amdgcn_mfma_f32_16x16x32_bf16(av[1], wv, acc16[1], 0, 0, 0);
            }
        }
        __syncthreads();  // all frag reads done before scratch aliasing

        // logits + dts -> LDS (scratch aliases ring; ring fully consumed)
        if (tid < 128) dts[tid] = dtreg;
        if (wc == 0) {
#pragma unroll
            for (int i = 0; i < 2; ++i)
#pragma unroll
                for (int r = 0; r < 4; ++r)
                    logitS[(wr * 32 + i * 16 + quad * 4 + r) * 17 + m16] = acc16[i][r];
        }
        __syncthreads();

        // per-row softmax-cumsum: fm half tid<128, im half tid 128..255.
        // Only chunk lidx needed per block (+ fsum for dist on nt==0).
        if (tid < 256) {
            const int row = tid & 127;
            const int m = m0 + row;
            const bool hi = tid >= 128;
            const float dt = hi ? dts[row] : dtreg;
            float z[8];
#pragma unroll
            for (int n = 0; n < 8; ++n)
                z[n] = logitS[row * 17 + soff + n] + b16r8[n] + dt * w16r8[n];
            float mx = z[0];
#pragma unroll
            for (int j = 1; j < 8; ++j) mx = fmaxf(mx, z[j]);
            float e[8], s = 0.f;
#pragma unroll
            for (int j = 0; j < 8; ++j) { e[j] = __expf(z[j] - mx); s += e[j]; }
            const float inv = __builtin_amdgcn_rcpf(s);
            if (!hi) {
                float run = 0.f, fsum = 0.f, val = 0.f;
#pragma unroll
                for (int j = 0; j < 8; ++j) {
                    run += e[j];
                    float fmv = run * inv;
                    if (j == lidx) val = fmv;
                    fsum += fmv;
                }
                fmimS[row * 2] = val;
                if (nt == 0) {
                    float d = 1.0f - fsum * 0.125f;
                    a.dist_out[(size_t)t * B + m] = d;
                    if (t >= T - KW) a.tmp_ds[(size_t)(t - (T - KW)) * B + m] = d;
                }
            } else {
                float run = 0.f, val = 0.f;
#pragma unroll
                for (int j = 7; j >= 0; --j) {
                    run += e[j];
                    if (j == lidx) val = run * inv;
                }
                fmimS[row * 2 + 1] = val;
            }
        }
        __syncthreads();

        // gates + cell update (c in regs); h -> LDS stage
#pragma unroll
        for (int i = 0; i < 2; ++i) {
#pragma unroll
            for (int r = 0; r < 4; ++r) {
                int rl = wr * 32 + i * 16 + quad * 4 + r;
                int m = m0 + rl;
                float dt = dts[rl];
                float fmv = fmimS[rl * 2];
                float imv = fmimS[rl * 2 + 1];
                float fg = fsigmoid_(acc[i][0][r] + bj[0] + dt * wj[0]);
                float ig = fsigmoid_(acc[i][1][r] + bj[1] + dt * wj[1]);
                float og = fsigmoid_(acc[i][2][r] + bj[2] + dt * wj[2]);
                float ci = ftanh_(acc[i][3][r] + bj[3] + dt * wj[3]);
                float ov = fmv * imv;
                float cl = creg[i][r];
                float cn = ov * (fg * cl + ig * ci) + (fmv - ov) * cl + (imv - ov) * ci;
                float hn = og * ftanh_(cn);
                creg[i][r] = cn;
                __hip_bfloat16 hb = __float2bfloat16(hn);
                hstageS[rl * 32 + (wc * 16 + m16)] = *(unsigned short*)&hb;
                if (t >= T - KW) a.tmp_h[((size_t)(t - (T - KW)) * B + m) * H + hcol] = hb;
            }
        }
        __syncthreads();

        // pack h pairs -> agent-scope atomic dword stores
        {
            const unsigned* hs32 = (const unsigned*)hstageS;
#pragma unroll
            for (int wds = 0; wds < 4; ++wds) {
                int wi = wds * 512 + tid;
                int row = wi >> 4, cp = wi & 15;
                unsigned v = hs32[row * 16 + cp];
                __hip_atomic_store(hout32 + (size_t)(m0 + row) * (H / 2) + nt * 16 + cp, v,
                                   __ATOMIC_RELAXED, __HIP_MEMORY_SCOPE_AGENT);
            }
        }

        __syncthreads();  // pack reads done + h stores drained (vmcnt0)
        if (t != T - 1) {
            // pre-issue next step's A(0) DMA + x reg preloads (fly during spin)
            const char* xn = xbT + (size_t)(t + 1) * 256;
            gl_lds16(xn, smem + o0);
            areg[1][0] = *(const ull*)(xn + 64);  areg[1][1] = *(const ull*)(xn + 72);
            areg[0][0] = *(const ull*)(xn + 128); areg[0][1] = *(const ull*)(xn + 136);
            // per-mt-group barrier (16 nt blocks = closed h-communication set)
            if (tid == 0) {
                unsigned* ctr = a.bar + (mt << 6);
                __hip_atomic_fetch_add(ctr, 1u, __ATOMIC_RELAXED, __HIP_MEMORY_SCOPE_AGENT);
                const unsigned tgt = 16u * (unsigned)(t + 1);
                for (int it = 0; it < (1 << 22); ++it) {
                    if (__hip_atomic_load(ctr, __ATOMIC_RELAXED, __HIP_MEMORY_SCOPE_AGENT) >= tgt) break;
                    __builtin_amdgcn_s_sleep(2);
                }
            }
            __syncthreads();  // releases block + drains pre-issued staging
        }
    }
}

// ---------- post (unchanged) ----------
__global__ __launch_bounds__(128) void post_local(
    const __hip_bfloat16* __restrict__ tmp_h, const float* __restrict__ tmp_dis,
    float* __restrict__ mean_h, __hip_bfloat16* __restrict__ Ahk)
{
    const int b = blockIdx.x;
    const int tid = threadIdx.x;
    __shared__ float ld[KW];
    if (tid == 0) {
        float cd[KW];
        float run = 0.f;
        for (int k = 0; k < KW; ++k) { run += tmp_dis[(size_t)k * B + b]; cd[k] = run; }
        float mx = cd[0];
        for (int k = 1; k < KW; ++k) mx = fmaxf(mx, cd[k]);
        float s = 0.f;
        for (int k = 0; k < KW; ++k) { cd[k] = expf(cd[k] - mx); s += cd[k]; }
        for (int k = 0; k < KW; ++k) ld[k] = cd[k] / s;
    }
    __syncthreads();
    float ldr[KW];
#pragma unroll
    for (int k = 0; k < KW; ++k) ldr[k] = ld[k];
    for (int h = tid; h < H; h += 128) {
        float s = 0.f;
#pragma unroll
        for (int k = 0; k < KW; ++k) {
            float v = __bfloat162float(tmp_h[((size_t)k * B + b) * H + h]) * ldr[k];
            s += v;
            Ahk[(size_t)b * RC + h * KW + k] = __float2bfloat16(v);
        }
        mean_h[(size_t)b * H + h] = s * (1.0f / KW);
    }
}

__global__ void theme1_k(const float* __restrict__ mean_h, const float* __restrict__ Ws,
                         const float* __restrict__ bs, float* __restrict__ t1)
{
    int idx = blockIdx.x * blockDim.x + threadIdx.x;
    if (idx >= B * HS) return;
    int b = idx / HS, j = idx % HS;
    float s = bs[j];
    const float* mh = mean_h + (size_t)b * H;
    for (int h = 0; h < H; ++h) s += mh[h] * Ws[(size_t)h * HS + j];
    t1[idx] = fmaxf(s, 0.f);
}

__global__ void theme2_k(const float* __restrict__ t1, const float* __restrict__ Wrs,
                         const float* __restrict__ brs, float* __restrict__ theme)
{
    int idx = blockIdx.x * blockDim.x + threadIdx.x;
    if (idx >= B * H) return;
    int b = idx / H, o = idx % H;
    float s = brs[o];
    const float* tv = t1 + (size_t)b * HS;
    for (int j = 0; j < HS; ++j) s += tv[j] * Wrs[(size_t)j * H + o];
    theme[idx] = 1.0f / (1.0f + expf(-s));
}

__global__ __launch_bounds__(256) void conv_split(
    const __hip_bfloat16* __restrict__ Ahk, const __hip_bfloat16* __restrict__ CWb,
    float* __restrict__ Pbuf)
{
    __shared__ __align__(16) unsigned short As2[128 * 64];
    __shared__ __align__(16) unsigned short Bs2[128 * 64];
    const int tid = threadIdx.x;
    const int wave = tid >> 6;
    const int wr = wave >> 1, wc = wave & 1;
    const int quad = (tid & 63) >> 4, m16 = tid & 15;
    const int n0 = blockIdx.x * 128, m0 = blockIdx.y * 128;
    const int ksb = blockIdx.z * (RC / KS);

    f32x4 acc[4][4] = {};
    for (int k0 = 0; k0 < RC / KS; k0 += 64) {
#pragma unroll
        for (int p = 0; p < 4; ++p) {
            int o = p * 4096 + tid * 16;
            int row = o >> 7, slot = (o >> 4) & 7;
            int kg = ksb + k0 + (slot ^ (row & 7)) * 8;
            gl_lds16((const unsigned short*)Ahk + (size_t)(m0 + row) * RC + kg, (char*)As2 + o);
            gl_lds16((const unsigned short*)CWb + (size_t)(n0 + row) * RC + kg, (char*)Bs2 + o);
        }
        __syncthreads();
#pragma unroll
        for (int c2 = 0; c2 < 2; ++c2) {
            const int k8 = c2 * 4 + quad;
            short8 av[4], bv[4];
#pragma unroll
            for (int i = 0; i < 4; ++i) {
                int arow2 = wr * 64 + i * 16 + m16;
                av[i] = *(const short8*)&As2[arow2 * 64 + (k8 ^ (arow2 & 7)) * 8];
            }
#pragma unroll
            for (int j = 0; j < 4; ++j) {
                int brow = wc * 64 + j * 16 + m16;
                bv[j] = *(const short8*)&Bs2[brow * 64 + (k8 ^ (brow & 7)) * 8];
            }
#pragma unroll
            for (int i = 0; i < 4; ++i)
#pragma unroll
                for (int j = 0; j < 4; ++j)
                    acc[i][j] = __builtin_amdgcn_mfma_f32_16x16x32_bf16(av[i], bv[j], acc[i][j], 0, 0, 0);
        }
        __syncthreads();
    }
    float* P = Pbuf + (size_t)blockIdx.z * B * H;
#pragma unroll
    for (int j = 0; j < 4; ++j) {
        const int col = n0 + wc * 64 + j * 16 + m16;
#pragma unroll
        for (int i = 0; i < 4; ++i) {
            const int rb = m0 + wr * 64 + i * 16 + quad * 4;
#pragma unroll
            for (int r = 0; r < 4; ++r)
                P[(size_t)(rb + r) * H + col] = acc[i][j][r];
        }
    }
}

__global__ void conv_reduce(const float* __restrict__ Pbuf, const float* __restrict__ conv_b,
                            const float* __restrict__ theme, float* __restrict__ out0)
{
    int i = blockIdx.x * blockDim.x + threadIdx.x;
    if (i >= B * H) return;
    float s = conv_b[i & (H - 1)];
#pragma unroll
    for (int ks = 0; ks < KS; ++ks) s += Pbuf[(size_t)ks * B * H + i];
    out0[i] = theme[i] * s;
}

} // namespace

extern "C" void kernel_launch(void* const* d_in, const int* in_sizes, int n_in,
                              void* d_out, int out_size, void* d_ws, size_t ws_size,
                              hipStream_t stream)
{
    (void)in_sizes; (void)n_in; (void)out_size; (void)ws_size;
    const float* x      = (const float*)d_in[0];
    const float* tme    = (const float*)d_in[1];
    const float* Wk     = (const float*)d_in[2];
    const float* bk     = (const float*)d_in[3];
    const float* Wr     = (const float*)d_in[4];
    const float* br     = (const float*)d_in[5];
    const float* Ws     = (const float*)d_in[6];
    const float* bs     = (const float*)d_in[7];
    const float* Wrs    = (const float*)d_in[8];
    const float* brs    = (const float*)d_in[9];
    const float* conv_w = (const float*)d_in[10];
    const float* conv_b = (const float*)d_in[11];

    float* out0 = (float*)d_out;
    float* dist_out = out0 + (size_t)B * H;

    // workspace carve (~163 MB)
    char* w = (char*)d_ws;
    __hip_bfloat16* WgT  = (__hip_bfloat16*)w; w += (size_t)16 * NROW * KIN * 2;
    __hip_bfloat16* xb   = (__hip_bfloat16*)w; w += (size_t)B * T * F * 2;
    __hip_bfloat16* CWb  = (__hip_bfloat16*)w; w += (size_t)H * RC * 2;
    __hip_bfloat16* Ahk  = (__hip_bfloat16*)w; w += (size_t)B * RC * 2;
    __hip_bfloat16* hb0  = (__hip_bfloat16*)w; w += (size_t)B * H * 2;
    __hip_bfloat16* hb1  = (__hip_bfloat16*)w; w += (size_t)B * H * 2;
    __hip_bfloat16* tmp_h = (__hip_bfloat16*)w; w += (size_t)KW * B * H * 2;
    float* biasg  = (float*)w; w += (size_t)NG * 4;
    float* wrowg  = (float*)w; w += (size_t)NG * 4;
    float* bias16 = (float*)w; w += 64;
    float* wrow16 = (float*)w; w += 64;
    float* tmp_ds = (float*)w; w += (size_t)KW * B * 4;
    float* mean_h = (float*)w; w += (size_t)B * H * 4;
    float* t1     = (float*)w; w += (size_t)B * HS * 4;
    float* theme  = (float*)w; w += (size_t)B * H * 4;
    float* Pbuf   = (float*)w; w += (size_t)KS * B * H * 4;
    float* tmeT   = (float*)w; w += (size_t)T * B * 4;
    unsigned* bar = (unsigned*)w; w += 4096;

    hipMemsetAsync(hb0, 0, (size_t)B * H * sizeof(__hip_bfloat16), stream);
    hipMemsetAsync(bar, 0, 4096, stream);

    prep_wgt<<<dim3(NG / 64, KIN / 64), 256, 0, stream>>>(Wk, Wr, WgT);
    prep_w16rep<<<(16 * 16 * KIN + 255) / 256, 256, 0, stream>>>(Wk, Wr, WgT);
    prep_small<<<1, 256, 0, stream>>>(Wk, bk, Wr, br, biasg, wrowg, bias16, wrow16);
    convert_x<<<((B * T * F / 4) + 255) / 256, 256, 0, stream>>>(x, xb);
    prep_convw<<<((H * RC / 4) + 255) / 256, 256, 0, stream>>>(conv_w, CWb);
    prep_tmet<<<dim3(B / 32, T / 32), 256, 0, stream>>>(tme, tmeT);

    {
        StepArgs sa;
        sa.xb = xb; sa.h0 = hb0; sa.h1 = hb1; sa.WgT = WgT;
        sa.biasg = biasg; sa.wrowg = wrowg; sa.bias16 = bias16; sa.wrow16 = wrow16;
        sa.tmeT = tmeT; sa.tmp_h = tmp_h; sa.tmp_ds = tmp_ds; sa.dist_out = dist_out;
        sa.bar = bar;
        persistent_step<<<256, 512, 0, stream>>>(sa);
    }

    post_local<<<B, 128, 0, stream>>>(tmp_h, tmp_ds, mean_h, Ahk);
    theme1_k<<<(B * HS + 255) / 256, 256, 0, stream>>>(mean_h, Ws, bs, t1);
    theme2_k<<<(B * H + 255) / 256, 256, 0, stream>>>(t1, Wrs, brs, theme);
    conv_split<<<dim3(H / 128, B / 128, KS), 256, 0, stream>>>(Ahk, CWb, Pbuf);
    conv_reduce<<<(B * H + 255) / 256, 256, 0, stream>>>(Pbuf, conv_b, theme, out0);
}

// Round 6
// 1744.021 us; speedup vs baseline: 1.8523x; 1.3500x over previous
//
#include <hip/hip_runtime.h>
#include <hip/hip_bf16.h>
#include <cstddef>
#include <cstdint>

namespace {

constexpr int B = 2048, T = 128, F = 128, H = 512, L = 8, KW = 10;
constexpr int GATES = 2064;
constexpr int NG = 2048;    // gate columns (permuted)
constexpr int KIN = 640;    // F + H
constexpr int HS = 85;      // H // 6
constexpr int RC = H * KW;  // 5120
constexpr int KS = 8;       // conv split-K slices
constexpr int NROW = 144;   // Bs rows per tile: 128 gates + 16 logit cols

// LDS layout for persistent_step (R2-verified, 155136+pad -> alloc 155136):
constexpr int BRES = 16384;      // resident B slices 0..11 (12 x 9216)
constexpr int BROT = 126976;     // rotating B ring, 3 x 9216 (slices 12..19)
constexpr int DTSO = 154624;     // dts 512 B (dedicated, never aliased)
constexpr int SMEM_SZ = 155136;

typedef __attribute__((ext_vector_type(8))) short short8;
typedef __attribute__((ext_vector_type(4))) float f32x4;
typedef unsigned long long ull;

__device__ __forceinline__ float fsigmoid_(float x) {
    return __builtin_amdgcn_rcpf(1.0f + __expf(-x));
}
__device__ __forceinline__ float ftanh_(float x) {
    return 1.0f - 2.0f * __builtin_amdgcn_rcpf(1.0f + __expf(2.0f * x));
}

__device__ __forceinline__ void gl_lds16(const void* g, void* l) {
    __builtin_amdgcn_global_load_lds(
        (const __attribute__((address_space(1))) unsigned int*)g,
        (__attribute__((address_space(3))) unsigned int*)l,
        16, 0, 0);
}

__device__ __forceinline__ ull h_atomic_load(const void* p) {
    return __hip_atomic_load((const ull*)p, __ATOMIC_RELAXED, __HIP_MEMORY_SCOPE_AGENT);
}

// ---------- prep (R2, unchanged) ----------
__global__ __launch_bounds__(256) void prep_wgt(
    const float* __restrict__ Wk, const float* __restrict__ Wr,
    __hip_bfloat16* __restrict__ WgT)
{
    __shared__ float tile[64 * 65];
    const int tid = threadIdx.x;
    const int c0 = blockIdx.x * 64, k0 = blockIdx.y * 64;
#pragma unroll
    for (int rep = 0; rep < 16; ++rep) {
        int e = rep * 256 + tid;
        int kl = e >> 6, cl = e & 63;
        int col = c0 + cl;
        int nt = col >> 7, cc = col & 127;
        int n = 16 + ((cc >> 4) & 3) * 512 + nt * 32 + ((cc >> 6) & 1) * 16 + (cc & 15);
        int k = k0 + kl;
        tile[kl * 65 + cl] = (k < F) ? Wk[(size_t)k * GATES + n] : Wr[(size_t)(k - F) * GATES + n];
    }
    __syncthreads();
    const int cl = tid >> 2, q = tid & 3;
    unsigned short buf[16];
#pragma unroll
    for (int i = 0; i < 16; ++i) {
        float f = tile[(q * 16 + i) * 65 + cl];
        __hip_bfloat16 bv = __float2bfloat16(f);
        buf[i] = *(unsigned short*)&bv;
    }
    int col = c0 + cl;
    int nt = col >> 7, rin = col & 127;
    unsigned short* dst = (unsigned short*)WgT + (size_t)nt * NROW * KIN + (size_t)rin * KIN + k0 + q * 16;
    *(short8*)dst = *(short8*)&buf[0];
    *(short8*)(dst + 8) = *(short8*)&buf[8];
}

__global__ void prep_w16rep(const float* __restrict__ Wk, const float* __restrict__ Wr,
                            __hip_bfloat16* __restrict__ WgT)
{
    int idx = blockIdx.x * blockDim.x + threadIdx.x;
    if (idx >= 16 * 16 * KIN) return;
    int nt = idx / (16 * KIN);
    int rem = idx % (16 * KIN);
    int n = rem / KIN, k = rem % KIN;
    float v = (k < F) ? Wk[(size_t)k * GATES + n] : Wr[(size_t)(k - F) * GATES + n];
    WgT[(size_t)nt * NROW * KIN + (size_t)(128 + n) * KIN + k] = __float2bfloat16(v);
}

__global__ void prep_small(const float* __restrict__ Wk, const float* __restrict__ bk,
                           const float* __restrict__ Wr, const float* __restrict__ br,
                           float* __restrict__ biasg, float* __restrict__ wrowg,
                           float* __restrict__ bias16, float* __restrict__ wrow16)
{
    const int total = 2 * NG + 32;
    for (int idx = threadIdx.x; idx < total; idx += 256) {
        if (idx < NG) {
            int col = idx;
            int nt = col >> 7, cc = col & 127;
            int n = 16 + ((cc >> 4) & 3) * 512 + nt * 32 + ((cc >> 6) & 1) * 16 + (cc & 15);
            biasg[col] = bk[n] + br[n];
        } else if (idx < 2 * NG) {
            int col = idx - NG;
            int nt = col >> 7, cc = col & 127;
            int n = 16 + ((cc >> 4) & 3) * 512 + nt * 32 + ((cc >> 6) & 1) * 16 + (cc & 15);
            wrowg[col] = Wk[(size_t)F * GATES + n] + Wr[(size_t)H * GATES + n];
        } else if (idx < 2 * NG + 16) {
            int n = idx - 2 * NG;
            bias16[n] = bk[n] + br[n];
        } else {
            int n = idx - 2 * NG - 16;
            wrow16[n] = Wk[(size_t)F * GATES + n] + Wr[(size_t)H * GATES + n];
        }
    }
}

__global__ void convert_x(const float* __restrict__ x, __hip_bfloat16* __restrict__ xb) {
    int i = blockIdx.x * blockDim.x + threadIdx.x;
    size_t o = (size_t)i * 4;
    if (o >= (size_t)B * T * F) return;
    float4 v = *(const float4*)(x + o);
    xb[o + 0] = __float2bfloat16(v.x);
    xb[o + 1] = __float2bfloat16(v.y);
    xb[o + 2] = __float2bfloat16(v.z);
    xb[o + 3] = __float2bfloat16(v.w);
}

__global__ void prep_convw(const float* __restrict__ conv_w, __hip_bfloat16* __restrict__ CWb) {
    int i = blockIdx.x * blockDim.x + threadIdx.x;
    if (i >= H * RC / 4) return;
    size_t o = (size_t)i * 4;
    float4 v = *(const float4*)(conv_w + o);
    CWb[o + 0] = __float2bfloat16(v.x);
    CWb[o + 1] = __float2bfloat16(v.y);
    CWb[o + 2] = __float2bfloat16(v.z);
    CWb[o + 3] = __float2bfloat16(v.w);
}

// tme [B,T] -> tmeT [T,B]
__global__ __launch_bounds__(256) void prep_tmet(const float* __restrict__ tin,
                                                 float* __restrict__ tout)
{
    __shared__ float tl[32][33];
    const int bb = blockIdx.x * 32, tt = blockIdx.y * 32;
    const int tx = threadIdx.x & 31, ty = threadIdx.x >> 5;
#pragma unroll
    for (int r = 0; r < 32; r += 8)
        tl[ty + r][tx] = tin[(size_t)(bb + ty + r) * T + tt + tx];
    __syncthreads();
#pragma unroll
    for (int r = 0; r < 32; r += 8)
        tout[(size_t)(tt + ty + r) * B + bb + tx] = tl[tx][ty + r];
}

// ---------- persistent fused step ----------
struct StepArgs {
    const __hip_bfloat16* xb;
    __hip_bfloat16* h0;
    __hip_bfloat16* h1;
    const __hip_bfloat16* WgT;
    const float* biasg;
    const float* wrowg;
    const float* bias16;
    const float* wrow16;
    const float* tmeT;   // [T, B]
    __hip_bfloat16* tmp_h;
    float* tmp_ds;
    float* dist_out;
    unsigned* bar;  // per-mt-group counters, 256 B apart
};

// R14 = EXACT R2 structure (verified 1550 us/step: 12 resident 9216-B slices,
// logit rows in LDS, 3-slot ring, spin pre-staging of B12/B13/A0, per-iter
// counted-vmcnt barriers, per-mt-group spin) + epilogue-only deltas:
//  (a) tme value held in a register across the k-loop (no step-top LDS stall);
//  (b) softmax stores only the 2 needed fmim floats/row (lidx = nt>>1);
//  (c) 8-wide per-thread bias16/wrow16 registers (soff).
__global__ __launch_bounds__(512, 2) void persistent_step(StepArgs a)
{
    __shared__ __align__(16) char smem[SMEM_SZ];
    // epilogue aliases (A bufs + rotating-B ring dead by epilogue;
    // resident B region 16384..126976 NEVER aliased):
    float* logitS = (float*)smem;                               // 8704 @0
    float* fmimS = (float*)(smem + BROT);                       // 1024 @126976
    unsigned short* hstageS = (unsigned short*)(smem + 135168); // 8192
    float* dts = (float*)(smem + DTSO);                         // 512 (dedicated)

    const int tid = threadIdx.x;
    const int wave = tid >> 6;
    const int wr = wave >> 1, wc = wave & 1;   // wr 0..3, wc 0..1
    const int quad = (tid & 63) >> 4, m16 = tid & 15;
    const int l = blockIdx.x;
    const int nt = ((l & 7) << 1) | ((l >> 3) & 1);  // same-nt -> same XCD
    const int mt = l >> 4;
    const int m0 = mt * 128;
    const int lidx = nt >> 1;   // block-constant chunk index

    // ---- per-thread staging geometry (A tile 128x32 bf16 = 8 KB; 16 B/thread)
    const int o0 = tid * 16;
    const int arow = o0 >> 6;                       // 64 B per row
    const int asl = ((((o0 >> 4) & 3) ^ ((arow >> 1) & 3)) << 3);  // k-elt offset
    const char* xbT = (const char*)a.xb + (size_t)(m0 + arow) * (T * F * 2) + asl * 2;
    const size_t hbyte = (size_t)(m0 + arow) * (H * 2) + asl * 2;
    // Bs: 144x32 bf16 = 9216 B; p0 = tid*16 (all), p1 = 8192 + tid*16 (tid<64)
    const unsigned short* wgt_tile = (const unsigned short*)a.WgT + (size_t)nt * NROW * KIN;
    const int brow0 = o0 >> 6;
    const int bsl0 = ((((o0 >> 4) & 3) ^ ((brow0 >> 1) & 3)) << 3);
    const char* bsT0 = (const char*)(wgt_tile + (size_t)brow0 * KIN + bsl0);
    const int ob1 = 8192 + tid * 16;
    const int brow1 = ob1 >> 6;
    const int bsl1 = ((((ob1 >> 4) & 3) ^ ((brow1 >> 1) & 3)) << 3);
    const char* bsT1 = (const char*)(wgt_tile + (size_t)brow1 * KIN + bsl1);
    const bool bv1 = (tid < 64);   // wave-uniform

    auto stageB = [&](int s, int bufbyte) {
        gl_lds16(bsT0 + s * 64, smem + bufbyte + o0);
        if (bv1) gl_lds16(bsT1 + s * 64, smem + bufbyte + ob1);
    };

    // t-invariant epilogue constants
    const int hcol = nt * 32 + wc * 16 + m16;
    float bj[4], wj[4];
#pragma unroll
    for (int j = 0; j < 4; ++j) {
        int col = nt * 128 + wc * 64 + j * 16 + m16;
        bj[j] = a.biasg[col];
        wj[j] = a.wrowg[col];
    }
    const int soff = (tid >= 128 && tid < 256) ? 8 : 0;
    float b16r8[8], w16r8[8];
#pragma unroll
    for (int n = 0; n < 8; ++n) { b16r8[n] = a.bias16[soff + n]; w16r8[n] = a.wrow16[soff + n]; }

    // frag-read addresses (two buffers each)
    const unsigned short* Abase = (const unsigned short*)smem;
    const unsigned short* Bbase = (const unsigned short*)(smem + BROT);

    float creg[2][4] = {};
    ull areg[2][2];

    // ---- prologue: stage resident B slices 0..11 once; pre-issue t=0 iter0
    {
#pragma unroll
        for (int s = 0; s < 12; ++s) stageB(s, BRES + s * 9216);
        gl_lds16(xbT, smem + o0);               // A(0)
        stageB(12, BROT + 0 * 9216);            // rot ring entries for t=0
        stageB(13, BROT + 1 * 9216);
        areg[1][0] = h_atomic_load(xbT + 64);  areg[1][1] = h_atomic_load(xbT + 72);
        areg[0][0] = h_atomic_load(xbT + 128); areg[0][1] = h_atomic_load(xbT + 136);
    }
    __syncthreads();  // drain all prologue staging before iter0 frag reads

#pragma unroll 1
    for (int t = 0; t < T; ++t) {
        const char* xt = xbT + (size_t)t * 256;
        const char* hs = (const char*)((t & 1) ? a.h1 : a.h0) + hbyte;
        unsigned* hout32 = (unsigned*)((t & 1) ? a.h0 : a.h1);

        // tme value into a register; LDS write deferred to epilogue
        float dtreg = 0.f;
        if (tid < 128) dtreg = a.tmeT[(size_t)t * B + m0 + tid];

        f32x4 acc[2][4] = {};
        f32x4 acc16[2] = {};

#pragma unroll
        for (int ki = 0; ki < 20; ++ki) {
            // Barrier + wait policy (R2-verified):
            //  ki 1..13 : B resident (0..11) or pre-staged+drained (12,13):
            //             lgkmcnt(0) only.
            //  ki 14..17: B(ki) DMA'd at iter ki-2. Ops issued after it:
            //             h(ki+1) x2 + B(ki+1) x c + h(ki+2) x2 -> vmcnt(4+c).
            //  ki 18    : after B(18): h(19) x2 + B(19) x c -> vmcnt(2+c).
            //  ki 19    : nothing issued after B(19) -> vmcnt(0).
            if (ki > 0) {
                if (ki <= 13) {
                    asm volatile("s_waitcnt lgkmcnt(0)" ::: "memory");
                } else if (ki <= 17) {
                    if (bv1) asm volatile("s_waitcnt vmcnt(6) lgkmcnt(0)" ::: "memory");
                    else     asm volatile("s_waitcnt vmcnt(5) lgkmcnt(0)" ::: "memory");
                } else if (ki == 18) {
                    if (bv1) asm volatile("s_waitcnt vmcnt(4) lgkmcnt(0)" ::: "memory");
                    else     asm volatile("s_waitcnt vmcnt(3) lgkmcnt(0)" ::: "memory");
                } else {
                    asm volatile("s_waitcnt vmcnt(0) lgkmcnt(0)" ::: "memory");
                }
                __builtin_amdgcn_s_barrier();
                __builtin_amdgcn_sched_barrier(0);
            }
            const int nxt = ki + 1;
            if (nxt < 20) {
                // stage A(nxt) from regs
                char* adst = smem + (nxt & 1) * 8192 + o0;
                *(ull*)adst = areg[nxt & 1][0];
                *(ull*)(adst + 8) = areg[nxt & 1][1];
            }
            // rotating-B DMA: slice s = ki+2 (14..19) -> ring buf (s-12)%3.
            if (ki >= 12 && ki <= 17) {
                const int s = ki + 2;
                stageB(s, BROT + ((s - 12) % 3) * 9216);
            }
            __builtin_amdgcn_sched_barrier(0);  // pin DMA before reg loads
            // reload areg set for iter ki+3
            const int fut = ki + 3;
            if (fut < 20) {
                if (fut <= 3) {
                    areg[fut & 1][0] = h_atomic_load(xt + fut * 64);
                    areg[fut & 1][1] = h_atomic_load(xt + fut * 64 + 8);
                } else {
                    areg[fut & 1][0] = h_atomic_load(hs + fut * 64 - 256);
                    areg[fut & 1][1] = h_atomic_load(hs + fut * 64 - 248);
                }
            }
            __builtin_amdgcn_sched_barrier(0);  // pin reg loads before frag reads
            // compute iter ki: A from dbuf ki&1, B from resident or ring
            const unsigned short* A = Abase + (ki & 1) * 4096;
            const unsigned short* Bb = (const unsigned short*)
                (smem + (ki < 12 ? BRES + ki * 9216 : BROT + ((ki - 12) % 3) * 9216));
            short8 av[2], bv[4];
#pragma unroll
            for (int i = 0; i < 2; ++i) {
                int ar = wr * 32 + i * 16 + m16;
                av[i] = *(const short8*)&A[ar * 32 + ((quad ^ ((ar >> 1) & 3)) << 3)];
            }
#pragma unroll
            for (int j = 0; j < 4; ++j) {
                int br = wc * 64 + j * 16 + m16;
                bv[j] = *(const short8*)&Bb[br * 32 + ((quad ^ ((br >> 1) & 3)) << 3)];
            }
#pragma unroll
            for (int i = 0; i < 2; ++i)
#pragma unroll
                for (int j = 0; j < 4; ++j)
                    acc[i][j] = __builtin_amdgcn_mfma_f32_16x16x32_bf16(av[i], bv[j], acc[i][j], 0, 0, 0);
            if (wc == 0) {
                int lr = 128 + m16;
                short8 wv = *(const short8*)&Bb[lr * 32 + ((quad ^ ((lr >> 1) & 3)) << 3)];
                acc16[0] = __builtin_amdgcn_mfma_f32_16x16x32_bf16(av[0], wv, acc16[0], 0, 0, 0);
                acc16[1] = __builtin_amdgcn_mfma_f32_16x16x32_bf16(av[1], wv, acc16[1], 0, 0, 0);
            }
        }
        __syncthreads();  // all frag reads done before scratch aliasing

        // logits + dts -> LDS (wc==0 waves: wr 0..3 cover 128 rows)
        if (tid < 128) dts[tid] = dtreg;
        if (wc == 0) {
#pragma unroll
            for (int i = 0; i < 2; ++i)
#pragma unroll
                for (int r = 0; r < 4; ++r)
                    logitS[(wr * 32 + i * 16 + quad * 4 + r) * 17 + m16] = acc16[i][r];
        }
        __syncthreads();

        // per-row softmax-cumsum: fm half tid<128, im half tid 128..255.
        // Only chunk lidx needed per block (+ fsum for dist on nt==0).
        if (tid < 256) {
            const int row = tid & 127;
            const int m = m0 + row;
            const bool hi = tid >= 128;
            const float dt = hi ? dts[row] : dtreg;
            float z[8];
#pragma unroll
            for (int n = 0; n < 8; ++n)
                z[n] = logitS[row * 17 + soff + n] + b16r8[n] + dt * w16r8[n];
            float mx = z[0];
#pragma unroll
            for (int j = 1; j < 8; ++j) mx = fmaxf(mx, z[j]);
            float e[8], s = 0.f;
#pragma unroll
            for (int j = 0; j < 8; ++j) { e[j] = __expf(z[j] - mx); s += e[j]; }
            const float inv = __builtin_amdgcn_rcpf(s);
            if (!hi) {
                float run = 0.f, fsum = 0.f, val = 0.f;
#pragma unroll
                for (int j = 0; j < 8; ++j) {
                    run += e[j];
                    float fmv = run * inv;
                    if (j == lidx) val = fmv;
                    fsum += fmv;
                }
                fmimS[row * 2] = val;
                if (nt == 0) {
                    float d = 1.0f - fsum * 0.125f;
                    a.dist_out[(size_t)t * B + m] = d;
                    if (t >= T - KW) a.tmp_ds[(size_t)(t - (T - KW)) * B + m] = d;
                }
            } else {
                float run = 0.f, val = 0.f;
#pragma unroll
                for (int j = 7; j >= 0; --j) {
                    run += e[j];
                    if (j == lidx) val = run * inv;
                }
                fmimS[row * 2 + 1] = val;
            }
        }
        __syncthreads();

        // gates + cell update (c in regs); h -> LDS stage
#pragma unroll
        for (int i = 0; i < 2; ++i) {
#pragma unroll
            for (int r = 0; r < 4; ++r) {
                int rl = wr * 32 + i * 16 + quad * 4 + r;
                int m = m0 + rl;
                float dt = dts[rl];
                float fmv = fmimS[rl * 2];
                float imv = fmimS[rl * 2 + 1];
                float fg = fsigmoid_(acc[i][0][r] + bj[0] + dt * wj[0]);
                float ig = fsigmoid_(acc[i][1][r] + bj[1] + dt * wj[1]);
                float og = fsigmoid_(acc[i][2][r] + bj[2] + dt * wj[2]);
                float ci = ftanh_(acc[i][3][r] + bj[3] + dt * wj[3]);
                float ov = fmv * imv;
                float cl = creg[i][r];
                float cn = ov * (fg * cl + ig * ci) + (fmv - ov) * cl + (imv - ov) * ci;
                float hn = og * ftanh_(cn);
                creg[i][r] = cn;
                __hip_bfloat16 hb = __float2bfloat16(hn);
                hstageS[rl * 32 + (wc * 16 + m16)] = *(unsigned short*)&hb;
                if (t >= T - KW) a.tmp_h[((size_t)(t - (T - KW)) * B + m) * H + hcol] = hb;
            }
        }
        __syncthreads();

        // pack h pairs -> agent-scope atomic dword stores
        {
            const unsigned* hs32 = (const unsigned*)hstageS;
#pragma unroll
            for (int wds = 0; wds < 4; ++wds) {
                int wi = wds * 512 + tid;
                int row = wi >> 4, cp = wi & 15;
                unsigned v = hs32[row * 16 + cp];
                __hip_atomic_store(hout32 + (size_t)(m0 + row) * (H / 2) + nt * 16 + cp, v,
                                   __ATOMIC_RELAXED, __HIP_MEMORY_SCOPE_AGENT);
            }
        }

        __syncthreads();  // pack reads done + h stores drained (vmcnt0)
        if (t != T - 1) {
            // pre-issue: ring slices + next step's A(0) + x preloads (fly in spin)
            const char* xn = xbT + (size_t)(t + 1) * 256;
            gl_lds16(xn, smem + o0);
            stageB(12, BROT + 0 * 9216);
            stageB(13, BROT + 1 * 9216);
            areg[1][0] = h_atomic_load(xn + 64);  areg[1][1] = h_atomic_load(xn + 72);
            areg[0][0] = h_atomic_load(xn + 128); areg[0][1] = h_atomic_load(xn + 136);
            // per-mt-group barrier (16 nt blocks = closed h-communication set)
            if (tid == 0) {
                unsigned* ctr = a.bar + (mt << 6);
                __hip_atomic_fetch_add(ctr, 1u, __ATOMIC_RELAXED, __HIP_MEMORY_SCOPE_AGENT);
                const unsigned tgt = 16u * (unsigned)(t + 1);
                for (int it = 0; it < (1 << 22); ++it) {
                    if (__hip_atomic_load(ctr, __ATOMIC_RELAXED, __HIP_MEMORY_SCOPE_AGENT) >= tgt) break;
                    __builtin_amdgcn_s_sleep(2);
                }
            }
            __syncthreads();  // releases block + drains pre-issued staging
        }
    }
}

// ---------- post (unchanged) ----------
__global__ __launch_bounds__(128) void post_local(
    const __hip_bfloat16* __restrict__ tmp_h, const float* __restrict__ tmp_dis,
    float* __restrict__ mean_h, __hip_bfloat16* __restrict__ Ahk)
{
    const int b = blockIdx.x;
    const int tid = threadIdx.x;
    __shared__ float ld[KW];
    if (tid == 0) {
        float cd[KW];
        float run = 0.f;
        for (int k = 0; k < KW; ++k) { run += tmp_dis[(size_t)k * B + b]; cd[k] = run; }
        float mx = cd[0];
        for (int k = 1; k < KW; ++k) mx = fmaxf(mx, cd[k]);
        float s = 0.f;
        for (int k = 0; k < KW; ++k) { cd[k] = expf(cd[k] - mx); s += cd[k]; }
        for (int k = 0; k < KW; ++k) ld[k] = cd[k] / s;
    }
    __syncthreads();
    float ldr[KW];
#pragma unroll
    for (int k = 0; k < KW; ++k) ldr[k] = ld[k];
    for (int h = tid; h < H; h += 128) {
        float s = 0.f;
#pragma unroll
        for (int k = 0; k < KW; ++k) {
            float v = __bfloat162float(tmp_h[((size_t)k * B + b) * H + h]) * ldr[k];
            s += v;
            Ahk[(size_t)b * RC + h * KW + k] = __float2bfloat16(v);
        }
        mean_h[(size_t)b * H + h] = s * (1.0f / KW);
    }
}

__global__ void theme1_k(const float* __restrict__ mean_h, const float* __restrict__ Ws,
                         const float* __restrict__ bs, float* __restrict__ t1)
{
    int idx = blockIdx.x * blockDim.x + threadIdx.x;
    if (idx >= B * HS) return;
    int b = idx / HS, j = idx % HS;
    float s = bs[j];
    const float* mh = mean_h + (size_t)b * H;
    for (int h = 0; h < H; ++h) s += mh[h] * Ws[(size_t)h * HS + j];
    t1[idx] = fmaxf(s, 0.f);
}

__global__ void theme2_k(const float* __restrict__ t1, const float* __restrict__ Wrs,
                         const float* __restrict__ brs, float* __restrict__ theme)
{
    int idx = blockIdx.x * blockDim.x + threadIdx.x;
    if (idx >= B * H) return;
    int b = idx / H, o = idx % H;
    float s = brs[o];
    const float* tv = t1 + (size_t)b * HS;
    for (int j = 0; j < HS; ++j) s += tv[j] * Wrs[(size_t)j * H + o];
    theme[idx] = 1.0f / (1.0f + expf(-s));
}

__global__ __launch_bounds__(256) void conv_split(
    const __hip_bfloat16* __restrict__ Ahk, const __hip_bfloat16* __restrict__ CWb,
    float* __restrict__ Pbuf)
{
    __shared__ __align__(16) unsigned short As2[128 * 64];
    __shared__ __align__(16) unsigned short Bs2[128 * 64];
    const int tid = threadIdx.x;
    const int wave = tid >> 6;
    const int wr = wave >> 1, wc = wave & 1;
    const int quad = (tid & 63) >> 4, m16 = tid & 15;
    const int n0 = blockIdx.x * 128, m0 = blockIdx.y * 128;
    const int ksb = blockIdx.z * (RC / KS);

    f32x4 acc[4][4] = {};
    for (int k0 = 0; k0 < RC / KS; k0 += 64) {
#pragma unroll
        for (int p = 0; p < 4; ++p) {
            int o = p * 4096 + tid * 16;
            int row = o >> 7, slot = (o >> 4) & 7;
            int kg = ksb + k0 + (slot ^ (row & 7)) * 8;
            gl_lds16((const unsigned short*)Ahk + (size_t)(m0 + row) * RC + kg, (char*)As2 + o);
            gl_lds16((const unsigned short*)CWb + (size_t)(n0 + row) * RC + kg, (char*)Bs2 + o);
        }
        __syncthreads();
#pragma unroll
        for (int c2 = 0; c2 < 2; ++c2) {
            const int k8 = c2 * 4 + quad;
            short8 av[4], bv[4];
#pragma unroll
            for (int i = 0; i < 4; ++i) {
                int arow2 = wr * 64 + i * 16 + m16;
                av[i] = *(const short8*)&As2[arow2 * 64 + (k8 ^ (arow2 & 7)) * 8];
            }
#pragma unroll
            for (int j = 0; j < 4; ++j) {
                int brow = wc * 64 + j * 16 + m16;
                bv[j] = *(const short8*)&Bs2[brow * 64 + (k8 ^ (brow & 7)) * 8];
            }
#pragma unroll
            for (int i = 0; i < 4; ++i)
#pragma unroll
                for (int j = 0; j < 4; ++j)
                    acc[i][j] = __builtin_amdgcn_mfma_f32_16x16x32_bf16(av[i], bv[j], acc[i][j], 0, 0, 0);
        }
        __syncthreads();
    }
    float* P = Pbuf + (size_t)blockIdx.z * B * H;
#pragma unroll
    for (int j = 0; j < 4; ++j) {
        const int col = n0 + wc * 64 + j * 16 + m16;
#pragma unroll
        for (int i = 0; i < 4; ++i) {
            const int rb = m0 + wr * 64 + i * 16 + quad * 4;
#pragma unroll
            for (int r = 0; r < 4; ++r)
                P[(size_t)(rb + r) * H + col] = acc[i][j][r];
        }
    }
}

__global__ void conv_reduce(const float* __restrict__ Pbuf, const float* __restrict__ conv_b,
                            const float* __restrict__ theme, float* __restrict__ out0)
{
    int i = blockIdx.x * blockDim.x + threadIdx.x;
    if (i >= B * H) return;
    float s = conv_b[i & (H - 1)];
#pragma unroll
    for (int ks = 0; ks < KS; ++ks) s += Pbuf[(size_t)ks * B * H + i];
    out0[i] = theme[i] * s;
}

} // namespace

extern "C" void kernel_launch(void* const* d_in, const int* in_sizes, int n_in,
                              void* d_out, int out_size, void* d_ws, size_t ws_size,
                              hipStream_t stream)
{
    (void)in_sizes; (void)n_in; (void)out_size; (void)ws_size;
    const float* x      = (const float*)d_in[0];
    const float* tme    = (const float*)d_in[1];
    const float* Wk     = (const float*)d_in[2];
    const float* bk     = (const float*)d_in[3];
    const float* Wr     = (const float*)d_in[4];
    const float* br     = (const float*)d_in[5];
    const float* Ws     = (const float*)d_in[6];
    const float* bs     = (const float*)d_in[7];
    const float* Wrs    = (const float*)d_in[8];
    const float* brs    = (const float*)d_in[9];
    const float* conv_w = (const float*)d_in[10];
    const float* conv_b = (const float*)d_in[11];

    float* out0 = (float*)d_out;
    float* dist_out = out0 + (size_t)B * H;

    // workspace carve (~163 MB)
    char* w = (char*)d_ws;
    __hip_bfloat16* WgT  = (__hip_bfloat16*)w; w += (size_t)16 * NROW * KIN * 2;
    __hip_bfloat16* xb   = (__hip_bfloat16*)w; w += (size_t)B * T * F * 2;
    __hip_bfloat16* CWb  = (__hip_bfloat16*)w; w += (size_t)H * RC * 2;
    __hip_bfloat16* Ahk  = (__hip_bfloat16*)w; w += (size_t)B * RC * 2;
    __hip_bfloat16* hb0  = (__hip_bfloat16*)w; w += (size_t)B * H * 2;
    __hip_bfloat16* hb1  = (__hip_bfloat16*)w; w += (size_t)B * H * 2;
    __hip_bfloat16* tmp_h = (__hip_bfloat16*)w; w += (size_t)KW * B * H * 2;
    float* biasg  = (float*)w; w += (size_t)NG * 4;
    float* wrowg  = (float*)w; w += (size_t)NG * 4;
    float* bias16 = (float*)w; w += 64;
    float* wrow16 = (float*)w; w += 64;
    float* tmp_ds = (float*)w; w += (size_t)KW * B * 4;
    float* mean_h = (float*)w; w += (size_t)B * H * 4;
    float* t1     = (float*)w; w += (size_t)B * HS * 4;
    float* theme  = (float*)w; w += (size_t)B * H * 4;
    float* Pbuf   = (float*)w; w += (size_t)KS * B * H * 4;
    float* tmeT   = (float*)w; w += (size_t)T * B * 4;
    unsigned* bar = (unsigned*)w; w += 4096;

    hipMemsetAsync(hb0, 0, (size_t)B * H * sizeof(__hip_bfloat16), stream);
    hipMemsetAsync(bar, 0, 4096, stream);

    prep_wgt<<<dim3(NG / 64, KIN / 64), 256, 0, stream>>>(Wk, Wr, WgT);
    prep_w16rep<<<(16 * 16 * KIN + 255) / 256, 256, 0, stream>>>(Wk, Wr, WgT);
    prep_small<<<1, 256, 0, stream>>>(Wk, bk, Wr, br, biasg, wrowg, bias16, wrow16);
    convert_x<<<((B * T * F / 4) + 255) / 256, 256, 0, stream>>>(x, xb);
    prep_convw<<<((H * RC / 4) + 255) / 256, 256, 0, stream>>>(conv_w, CWb);
    prep_tmet<<<dim3(B / 32, T / 32), 256, 0, stream>>>(tme, tmeT);

    {
        StepArgs sa;
        sa.xb = xb; sa.h0 = hb0; sa.h1 = hb1; sa.WgT = WgT;
        sa.biasg = biasg; sa.wrowg = wrowg; sa.bias16 = bias16; sa.wrow16 = wrow16;
        sa.tmeT = tmeT; sa.tmp_h = tmp_h; sa.tmp_ds = tmp_ds; sa.dist_out = dist_out;
        sa.bar = bar;
        persistent_step<<<256, 512, 0, stream>>>(sa);
    }

    post_local<<<B, 128, 0, stream>>>(tmp_h, tmp_ds, mean_h, Ahk);
    theme1_k<<<(B * HS + 255) / 256, 256, 0, stream>>>(mean_h, Ws, bs, t1);
    theme2_k<<<(B * H + 255) / 256, 256, 0, stream>>>(t1, Wrs, brs, theme);
    conv_split<<<dim3(H / 128, B / 128, KS), 256, 0, stream>>>(Ahk, CWb, Pbuf);
    conv_reduce<<<(B * H + 255) / 256, 256, 0, stream>>>(Pbuf, conv_b, theme, out0);
}